// Round 11
// baseline (292.555 us; speedup 1.0000x reference)
//
#include <hip/hip_runtime.h>
#include <hip/hip_bf16.h>

#define DEV static __device__ __forceinline__

constexpr int F1 = 128;   // input features
constexpr int H1 = 8;     // heads layer1
constexpr int C  = 64;    // channels per head
constexpr int B  = 64;    // graphs
constexpr int K  = 10;    // classes
constexpr float NEG = 0.2f;
constexpr unsigned SMASK = 0x07FFFFFFu;   // col[] low bits = src id; bits 27-30 = dest&15

typedef __attribute__((ext_vector_type(8))) short short8;
typedef __attribute__((ext_vector_type(4))) float floatx4;

DEV float b2f(__hip_bfloat16 x) { return __bfloat162float(x); }
DEV float elu1(float v) { return v > 0.f ? v : (__expf(v) - 1.f); }
DEV unsigned short f2bbits(float f) {
  __hip_bfloat16 b = __float2bfloat16(f);
  return *(unsigned short*)&b;
}
DEV float blo(unsigned u) { return __uint_as_float(u << 16); }
DEV float bhi(unsigned u) { return __uint_as_float(u & 0xffff0000u); }
DEV float bu(unsigned short u) { return __uint_as_float(((unsigned)u) << 16); }
DEV unsigned pack2(float lo, float hi) {
  return (unsigned)f2bbits(lo) | ((unsigned)f2bbits(hi) << 16);
}
// 1/x via v_rcp_f32 + one Newton step
DEV float rcp_nr(float x) {
  float r = __builtin_amdgcn_rcpf(x);
  return r * (2.f - x * r);
}

// out1 PERMUTED layout: position p = hp*128 + l16*8 + nt  <->  natural channel
// c = hp*128 + nt*16 + l16. W2frag k-rows and b1 permuted to match.
// W1frag k is NATURAL.

// Self-detection: thread 0 samples 128 even-index bf16 reinterps of x.
DEV int detect_dev(const void* xraw, int* lds) {
  if (threadIdx.x == 0) {
    const __hip_bfloat16* xb = (const __hip_bfloat16*)xraw;
    int bad = 0;
    for (int i = 0; i < 128; ++i) {
      float v = b2f(xb[2 * i]);
      if (!(fabsf(v) < 1e4f)) bad++;
    }
    *lds = (bad < 13) ? 1 : 0;     // 1 = bf16, 0 = f32
  }
  __syncthreads();
  return *lds;
}

#define CVT(p, i) (isbf ? b2f(((const __hip_bfloat16*)(p))[i]) : ((const float*)(p))[i])

// ---------- fused prep ----------
__global__ void fused_prep_kernel(const void* x_raw, const void* w1raw,
                                  const void* as1r, const void* ad1r, const void* b1r,
                                  const void* w2raw,
                                  const void* as2r, const void* ad2r, const void* b2r,
                                  const void* l1wr, const void* l1br,
                                  const void* l2wr, const void* l2br,
                                  unsigned short* __restrict__ xbf,
                                  unsigned short* __restrict__ w1frag,
                                  unsigned short* __restrict__ w2frag,
                                  unsigned short* __restrict__ vfrag,
                                  float* __restrict__ wts,
                                  int* __restrict__ deg,
                                  float* __restrict__ pooled,
                                  int nX, int N) {
  __shared__ int fl;
  int isbf = detect_dev(x_raw, &fl);
  int gid = blockIdx.x * 256 + threadIdx.x;
  int stride = gridDim.x * 256;

  // VECTORIZED xbf copy: 16B per thread-iteration (G13 — scalar b16 was ~20us)
  int ng = nX >> 3;
  if (isbf) {
    const uint4* src = (const uint4*)x_raw;
    uint4* dst = (uint4*)xbf;
    for (int i = gid; i < ng; i += stride) dst[i] = src[i];
  } else {
    const float4* src = (const float4*)x_raw;
    uint4* dst = (uint4*)xbf;
    for (int i = gid; i < ng; i += stride) {
      float4 a = src[2 * i], b = src[2 * i + 1];
      uint4 o;
      o.x = pack2(a.x, a.y); o.y = pack2(a.z, a.w);
      o.z = pack2(b.x, b.y); o.w = pack2(b.z, b.w);
      dst[i] = o;
    }
  }
  for (int i = ng * 8 + gid; i < nX; i += stride)   // tail (nX%8, normally 0)
    xbf[i] = isbf ? ((const unsigned short*)x_raw)[i]
                  : f2bbits(((const float*)x_raw)[i]);

  // b1 stored PERMUTED: wts[1024 + p] = b1[c_nat(p)]
  for (int i = gid; i < 512;  i += stride) {
    int hp = i >> 7, l16 = (i >> 3) & 15, nt = i & 7;
    int c = hp * 128 + nt * 16 + l16;
    wts[1024 + i] = CVT(b1r, c);
  }
  for (int i = gid; i < 64;   i += stride) wts[1536 + i] = CVT(as2r, i);
  for (int i = gid; i < 64;   i += stride) wts[1600 + i] = CVT(ad2r, i);
  for (int i = gid; i < 64;   i += stride) wts[1664 + i] = CVT(b2r, i);
  for (int i = gid; i < 4096; i += stride) wts[1728 + i] = CVT(l1wr, i);
  for (int i = gid; i < 64;   i += stride) wts[5824 + i] = CVT(l1br, i);
  for (int i = gid; i < 640;  i += stride) wts[5888 + i] = CVT(l2wr, i);
  for (int i = gid; i < 10;   i += stride) wts[6528 + i] = CVT(l2br, i);
  // W1frag NATURAL k
  for (int t = gid; t < 8192; t += stride) {
    int lane = t & 63, ks = (t >> 6) & 3, nt = t >> 8;
    for (int j = 0; j < 8; ++j) {
      int k = ks * 32 + (lane >> 4) * 8 + j;
      int n = nt * 16 + (lane & 15);
      w1frag[t * 8 + j] = f2bbits(CVT(w1raw, k * 512 + n));
    }
  }
  // W2frag with PERMUTED k: k index in fragment = position p; fetch W2[c_nat(p)]
  for (int t = gid; t < 4096; t += stride) {
    int lane = t & 63, nt = (t >> 6) & 3, ks = t >> 8;
    for (int j = 0; j < 8; ++j) {
      int p = ks * 32 + (lane >> 4) * 8 + j;          // permuted position
      int hp = p >> 7, pl16 = (p >> 3) & 15, pnt = p & 7;
      int k = hp * 128 + pnt * 16 + pl16;             // natural channel
      int n = nt * 16 + (lane & 15);
      w2frag[t * 8 + j] = f2bbits(CVT(w2raw, k * 64 + n));
    }
  }
  // Vfrag: B-fragment of V[128 x 16], V[:,n<8] = W1 head-n col @ att_src[n],
  // V[:,n>=8] = same with att_dst. a_s/a_d = x @ V.
  for (int t = gid; t < 2048; t += stride) {
    int j = t & 7, lane = (t >> 3) & 63, ks = t >> 9;
    int k = ks * 32 + (lane >> 4) * 8 + j;
    int n = lane & 15;
    int hh = (n < 8) ? n : (n - 8);
    float s = 0.f;
    if (n < 8) {
      for (int c = 0; c < 64; ++c)
        s += CVT(w1raw, k * 512 + hh * 64 + c) * CVT(as1r, hh * 64 + c);
    } else {
      for (int c = 0; c < 64; ++c)
        s += CVT(w1raw, k * 512 + hh * 64 + c) * CVT(ad1r, hh * 64 + c);
    }
    vfrag[(ks * 64 + lane) * 8 + j] = f2bbits(s);
  }
  for (int i = gid; i < N; i += stride) deg[i] = 0;
  for (int i = gid; i < B * C; i += stride) pooled[i] = 0.f;
}

// ---------- FUSED: att_scalars (blocks < attBlocks) + degree count ----------
__global__ __launch_bounds__(256) void deg_att_kernel(
    const int* __restrict__ ei, int E, int Etot, int* __restrict__ deg,
    const unsigned short* __restrict__ xbf,     // N x 128 bf16
    const unsigned short* __restrict__ vfrag,   // [4ks][64][8] bf16
    float* __restrict__ a_s, float* __restrict__ a_d,   // N x 8
    int N, int attBlocks) {
  if ((int)blockIdx.x >= attBlocks) {
    int e = ((int)blockIdx.x - attBlocks) * 256 + threadIdx.x;
    if (e < Etot) {
      int d = (e < E) ? ei[E + e] : e - E;
      atomicAdd(&deg[d], 1);
    }
    return;
  }
  int t = threadIdx.x, w = t >> 6, lane = t & 63;
  int quad = lane >> 4, l16 = lane & 15;
  int row0 = blockIdx.x * 64 + w * 16;

  floatx4 acc = {};
  int rl = row0 + l16; if (rl >= N) rl = N - 1;
  const unsigned short* xp = xbf + (size_t)rl * 128 + quad * 8;
#pragma unroll
  for (int ks = 0; ks < 4; ++ks) {
    short8 a = *(const short8*)(xp + ks * 32);
    short8 b = *(const short8*)&vfrag[(ks * 64 + lane) * 8];
    acc = __builtin_amdgcn_mfma_f32_16x16x32_bf16(a, b, acc, 0, 0, 0);
  }
#pragma unroll
  for (int r = 0; r < 4; ++r) {
    int row = row0 + quad * 4 + r;
    if (row < N) {
      if (l16 < 8) a_s[(size_t)row * 8 + l16] = acc[r];
      else         a_d[(size_t)row * 8 + (l16 - 8)] = acc[r];
    }
  }
}

// ---------- CSR scans ----------
__global__ void scan_block_kernel(const int* __restrict__ deg,
                                  int* __restrict__ local,
                                  int* __restrict__ bsum, int N) {
  __shared__ int tmp[256];
  int t = threadIdx.x;
  int i = blockIdx.x * 256 + t;
  int v = (i < N) ? deg[i] : 0;
  tmp[t] = v;
  __syncthreads();
  for (int off = 1; off < 256; off <<= 1) {
    int u = (t >= off) ? tmp[t - off] : 0;
    __syncthreads();
    tmp[t] += u;
    __syncthreads();
  }
  if (i < N) local[i] = tmp[t] - v;
  if (t == 255) bsum[blockIdx.x] = tmp[255];
}

__global__ void scan_finish_kernel(const int* __restrict__ local,
                                   const int* __restrict__ bsum, int nb,
                                   int* __restrict__ rowptr,
                                   int* __restrict__ cursor, int N, int Etot) {
  __shared__ int tmp[256];
  __shared__ int offs;
  int t = threadIdx.x;
  int v0 = (t < nb) ? bsum[t] : 0;
  tmp[t] = v0;
  __syncthreads();
  for (int off = 1; off < 256; off <<= 1) {
    int u = (t >= off) ? tmp[t - off] : 0;
    __syncthreads();
    tmp[t] += u;
    __syncthreads();
  }
  if (t == (int)blockIdx.x) offs = tmp[t] - v0;
  __syncthreads();
  int i = blockIdx.x * 256 + t;
  if (i < N) {
    int r = local[i] + offs;
    rowptr[i] = r;
    cursor[i] = r;
  }
  if (i == 0) rowptr[N] = Etot;
}

// ---------- CSR fill + per-edge softmax weights (bf16 x8, CSR slot order) ----
// col[pos] = src | (dest&15)<<27. No hot-address atomics (round-7 lesson).
__global__ void fill_weight_kernel(const int* __restrict__ ei, int E, int Etot,
                                   const float* __restrict__ a_s,
                                   const float* __restrict__ a_d,
                                   int* __restrict__ cursor,
                                   int* __restrict__ col,
                                   unsigned short* __restrict__ wedge) {
  int e = blockIdx.x * 256 + threadIdx.x;
  if (e >= Etot) return;
  int s, d;
  if (e < E) { s = ei[e]; d = ei[E + e]; } else { s = d = e - E; }
  int pos = atomicAdd(&cursor[d], 1);
  col[pos] = s | ((d & 15) << 27);
  float4 s0 = *(const float4*)(a_s + (size_t)s * 8);
  float4 s1 = *(const float4*)(a_s + (size_t)s * 8 + 4);
  float4 d0 = *(const float4*)(a_d + (size_t)d * 8);
  float4 d1 = *(const float4*)(a_d + (size_t)d * 8 + 4);
  float v, w0, w1, w2, w3, w4, w5, w6, w7;
  v = s0.x + d0.x; v = v > 0.f ? v : NEG * v; w0 = __expf(v);
  v = s0.y + d0.y; v = v > 0.f ? v : NEG * v; w1 = __expf(v);
  v = s0.z + d0.z; v = v > 0.f ? v : NEG * v; w2 = __expf(v);
  v = s0.w + d0.w; v = v > 0.f ? v : NEG * v; w3 = __expf(v);
  v = s1.x + d1.x; v = v > 0.f ? v : NEG * v; w4 = __expf(v);
  v = s1.y + d1.y; v = v > 0.f ? v : NEG * v; w5 = __expf(v);
  v = s1.z + d1.z; v = v > 0.f ? v : NEG * v; w6 = __expf(v);
  v = s1.w + d1.w; v = v > 0.f ? v : NEG * v; w7 = __expf(v);
  uint4 o;
  o.x = pack2(w0, w1); o.y = pack2(w2, w3);
  o.z = pack2(w4, w5); o.w = pack2(w6, w7);
  *(uint4*)(wedge + (size_t)pos * 8) = o;
}

// ---------- MFMA-based x-space aggregation + W1 GEMM -> out1 ----------
// CHUNK = 64 edge slots = two independent 32-slot halves, each using the
// round-9-proven {XgT 8K, Wm 8K} layout & swizzle verbatim. One barrier per
// 64 edges (halved). Pipelined (T14): write prefetched chunk c -> buf[c&1],
// issue chunk c+1 loads, barrier, 18 MFMA. LDS: 2 x 32K dbuf UNION AggP 34.8K.
__global__ __launch_bounds__(512, 4) void aggx_gemm1_kernel(
    const unsigned short* __restrict__ xbf,     // N x 128 bf16
    const unsigned short* __restrict__ W1frag,  // [32][4][64][8] bf16 (natural k)
    const int* __restrict__ rowptr,
    const int* __restrict__ col,                // src | dl<<27
    const unsigned short* __restrict__ wedge,   // Etot x 8 bf16 (CSR order)
    const float* __restrict__ bias_perm,        // 512, PERMUTED
    unsigned short* __restrict__ out1,          // N x 512 bf16 (PERMUTED)
    int N) {
  __shared__ __align__(16) char LB[65536];              // 2 x 32K dbuf / AggP
  unsigned short* AggP = (unsigned short*)LB;           // 34.8 KB (epilogue)

  int t = threadIdx.x, w = t >> 6, lane = t & 63;
  int q = lane >> 4, n = lane & 15;
  int dbase = blockIdx.x * 16;

  int R0 = rowptr[dbase];
  int R1 = rowptr[min(dbase + 16, N)];
  int nch = (R1 - R0 + 63) >> 6;

  // staging ids: kp = edge-pair (0..15), pp = feature-quad (0..31)
  int kp = t >> 5, pp = t & 31;
  int skey = (pp & 7) << 4;              // = ((f>>2)&7)<<4 for f = 4*pp+df
  // wmat ids
  int dw = t >> 5, kw = t & 31;

  // ones B-fragment: B[k][n] = (n==0) ? 1.0bf16 : 0
  short8 onesf = {};
  if (n == 0) {
#pragma unroll
    for (int j = 0; j < 8; ++j) onesf[j] = (short)0x3F80;
  }

  floatx4 accw[8] = {};
  floatx4 accdn = {};

  // prefetched chunk data (two 32-slot halves)
  uint2 pxa0, pxb0, pxa1, pxb1;
  uint4 pwv0, pwv1;
  int pcv0, pcv1;

  auto prefetch = [&](int ebase) {
    int eA = ebase + 2 * kp, eB = ebase + 32 + 2 * kp;
    int a0 = min(eA, R1 - 1), a1 = min(eA + 1, R1 - 1);
    int b0 = min(eB, R1 - 1), b1 = min(eB + 1, R1 - 1);
    pxa0 = *(const uint2*)(xbf + (size_t)(col[a0] & SMASK) * 128 + pp * 4);
    pxb0 = *(const uint2*)(xbf + (size_t)(col[a1] & SMASK) * 128 + pp * 4);
    pxa1 = *(const uint2*)(xbf + (size_t)(col[b0] & SMASK) * 128 + pp * 4);
    pxb1 = *(const uint2*)(xbf + (size_t)(col[b1] & SMASK) * 128 + pp * 4);
    int ewA = min(ebase + kw, R1 - 1), ewB = min(ebase + 32 + kw, R1 - 1);
    pcv0 = col[ewA]; pwv0 = *(const uint4*)(wedge + (size_t)ewA * 8);
    pcv1 = col[ewB]; pwv1 = *(const uint4*)(wedge + (size_t)ewB * 8);
  };
  prefetch(R0);

  for (int c = 0; c < nch; ++c) {
    char* Lb = LB + (c & 1) * 32768;
    int ebase = R0 + c * 64;

    // ---- phase A: write prefetched chunk into buf[c&1] (round-9 layout x2) --
    {
      int base = 256 * pp + 4 * kp;
      // half A -> XgT_a at Lb
      unsigned u0 = (pxa0.x & 0xffffu) | (pxb0.x << 16);
      unsigned u1 = (pxa0.x >> 16) | (pxb0.x & 0xffff0000u);
      unsigned u2 = (pxa0.y & 0xffffu) | (pxb0.y << 16);
      unsigned u3 = (pxa0.y >> 16) | (pxb0.y & 0xffff0000u);
      *(unsigned*)(Lb + ((base)       ^ skey)) = u0;
      *(unsigned*)(Lb + ((base + 64)  ^ skey)) = u1;
      *(unsigned*)(Lb + ((base + 128) ^ skey)) = u2;
      *(unsigned*)(Lb + ((base + 192) ^ skey)) = u3;
      // half B -> XgT_b at Lb + 8192
      char* Lb2 = Lb + 8192;
      unsigned v0 = (pxa1.x & 0xffffu) | (pxb1.x << 16);
      unsigned v1 = (pxa1.x >> 16) | (pxb1.x & 0xffff0000u);
      unsigned v2 = (pxa1.y & 0xffffu) | (pxb1.y << 16);
      unsigned v3 = (pxa1.y >> 16) | (pxb1.y & 0xffff0000u);
      *(unsigned*)(Lb2 + ((base)       ^ skey)) = v0;
      *(unsigned*)(Lb2 + ((base + 64)  ^ skey)) = v1;
      *(unsigned*)(Lb2 + ((base + 128) ^ skey)) = v2;
      *(unsigned*)(Lb2 + ((base + 192) ^ skey)) = v3;
      // Wm halves
      {
        int ew = ebase + kw;
        int dl = (pcv0 >> 27) & 15;
        bool mine = (ew < R1) && (dl == dw);
        unsigned short* wmp = (unsigned short*)(Lb + 16384) + dw * 32 + kw;
        wmp[0]    = mine ? (unsigned short)(pwv0.x & 0xffff) : 0;
        wmp[512]  = mine ? (unsigned short)(pwv0.x >> 16)    : 0;
        wmp[1024] = mine ? (unsigned short)(pwv0.y & 0xffff) : 0;
        wmp[1536] = mine ? (unsigned short)(pwv0.y >> 16)    : 0;
        wmp[2048] = mine ? (unsigned short)(pwv0.z & 0xffff) : 0;
        wmp[2560] = mine ? (unsigned short)(pwv0.z >> 16)    : 0;
        wmp[3072] = mine ? (unsigned short)(pwv0.w & 0xffff) : 0;
        wmp[3584] = mine ? (unsigned short)(pwv0.w >> 16)    : 0;
      }
      {
        int ew = ebase + 32 + kw;
        int dl = (pcv1 >> 27) & 15;
        bool mine = (ew < R1) && (dl == dw);
        unsigned short* wmp = (unsigned short*)(Lb + 24576) + dw * 32 + kw;
        wmp[0]    = mine ? (unsigned short)(pwv1.x & 0xffff) : 0;
        wmp[512]  = mine ? (unsigned short)(pwv1.x >> 16)    : 0;
        wmp[1024] = mine ? (unsigned short)(pwv1.y & 0xffff) : 0;
        wmp[1536] = mine ? (unsigned short)(pwv1.y >> 16)    : 0;
        wmp[2048] = mine ? (unsigned short)(pwv1.z & 0xffff) : 0;
        wmp[2560] = mine ? (unsigned short)(pwv1.z >> 16)    : 0;
        wmp[3072] = mine ? (unsigned short)(pwv1.w & 0xffff) : 0;
        wmp[3584] = mine ? (unsigned short)(pwv1.w >> 16)    : 0;
      }
    }
    // ---- phase B: issue chunk c+1 loads (latency hides under MFMA) ----
    if (c + 1 < nch) prefetch(R0 + (c + 1) * 64);
    __syncthreads();

    // ---- phase C: MFMA from buf[c&1]; wave w = head w; 2 k-halves ----
#pragma unroll
    for (int ks = 0; ks < 2; ++ks) {
      const unsigned short* Wmk = (const unsigned short*)(Lb + 16384 + ks * 8192);
      const char* XgTk = Lb + ks * 8192;
      short8 af = *(const short8*)(Wmk + w * 512 + n * 32 + 8 * q);
      accdn = __builtin_amdgcn_mfma_f32_16x16x32_bf16(af, onesf, accdn, 0, 0, 0);
#pragma unroll
      for (int ft = 0; ft < 8; ++ft) {
        int f = ft * 16 + n;
        int bb = f * 64 + 16 * q;
        bb ^= ((f >> 2) & 7) << 4;
        short8 bfr = *(const short8*)(XgTk + bb);
        accw[ft] = __builtin_amdgcn_mfma_f32_16x16x32_bf16(af, bfr, accw[ft], 0, 0, 0);
      }
    }
  }

  __syncthreads();                         // last MFMA reads done before AggP

  // ---- epilogue: normalize (denominator from accdn col 0), write AggP ----
  {
    float dnv[4];
#pragma unroll
    for (int r = 0; r < 4; ++r) {
      float dr = __shfl(accdn[r], lane & 48);      // broadcast col-0 lane of quad
      dnv[r] = rcp_nr(dr + 1e-16f);
    }
#pragma unroll
    for (int ft = 0; ft < 8; ++ft)
#pragma unroll
      for (int r = 0; r < 4; ++r)
        AggP[w * 2176 + (4 * q + r) * 136 + ft * 16 + n] =
            f2bbits(accw[ft][r] * dnv[r]);
  }
  __syncthreads();

  // ---- phase 3: per-head W1 GEMM, bias + ELU, permuted store ----
  {
    int hp = w >> 1, qq = w & 1;
    floatx4 acc2[4] = {};
    const unsigned short* Bp = W1frag + (size_t)hp * 16384;
#pragma unroll
    for (int ks = 0; ks < 4; ++ks) {
      short8 a2 = *(const short8*)&AggP[w * 2176 + n * 136 + ks * 32 + q * 8];
#pragma unroll
      for (int j = 0; j < 4; ++j) {
        int nt = qq * 4 + j;
        short8 b2 = *(const short8*)&Bp[((nt * 4 + ks) * 64 + lane) * 8];
        acc2[j] = __builtin_amdgcn_mfma_f32_16x16x32_bf16(a2, b2, acc2[j], 0, 0, 0);
      }
    }
    float4 bq = *(const float4*)&bias_perm[hp * 128 + n * 8 + qq * 4];
#pragma unroll
    for (int r = 0; r < 4; ++r) {
      int row = dbase + 4 * q + r;
      if (row < N) {
        uint2 o;
        o.x = pack2(elu1(acc2[0][r] + bq.x), elu1(acc2[1][r] + bq.y));
        o.y = pack2(elu1(acc2[2][r] + bq.z), elu1(acc2[3][r] + bq.w));
        *(uint2*)&out1[(size_t)row * 512 + hp * 128 + n * 8 + qq * 4] = o;
      }
    }
  }
}

// ---------- layer 2: MFMA bf16 GEMM (k-dim permuted to match out1bf) ----------
__global__ __launch_bounds__(256) void gemm2_mfma_kernel(
    const unsigned short* __restrict__ x2bf,    // N x 512 bf16 (PERMUTED k)
    const unsigned short* __restrict__ W2frag,  // [16ks][4nt][64][8] bf16 (perm k)
    const float* __restrict__ att_src,          // 64
    const float* __restrict__ att_dst,
    unsigned short* __restrict__ h2,            // N x 64 bf16 (natural)
    float* __restrict__ a_s, float* __restrict__ a_d,  // N
    int N) {
  int t = threadIdx.x;
  int w = t >> 6, lane = t & 63;
  int quad = lane >> 4, l16 = lane & 15;
  int rowbase = blockIdx.x * 64 + w * 16;

  floatx4 acc[4] = {};
  int r0 = rowbase + l16; if (r0 >= N) r0 = N - 1;
  const unsigned short* p0 = x2bf + (size_t)r0 * 512 + quad * 8;
#pragma unroll
  for (int ks = 0; ks < 16; ++ks) {
    short8 a0 = *(const short8*)(p0 + ks * 32);
#pragma unroll
    for (int nt = 0; nt < 4; ++nt) {
      short8 b = *(const short8*)&W2frag[((ks * 4 + nt) * 64 + lane) * 8];
      acc[nt] = __builtin_amdgcn_mfma_f32_16x16x32_bf16(a0, b, acc[nt], 0, 0, 0);
    }
  }

  float asw[4], adw[4];
#pragma unroll
  for (int nt = 0; nt < 4; ++nt) {
    asw[nt] = att_src[nt * 16 + l16];
    adw[nt] = att_dst[nt * 16 + l16];
  }
  float ps[4] = {}, pd[4] = {};
#pragma unroll
  for (int nt = 0; nt < 4; ++nt)
#pragma unroll
    for (int r = 0; r < 4; ++r) {
      float v = acc[nt][r];
      int row = rowbase + quad * 4 + r;
      if (row < N) h2[(size_t)row * 64 + nt * 16 + l16] = f2bbits(v);
      ps[r] += v * asw[nt];
      pd[r] += v * adw[nt];
    }
#pragma unroll
  for (int r = 0; r < 4; ++r) {
    float p = ps[r], q = pd[r];
#pragma unroll
    for (int off = 1; off < 16; off <<= 1) {
      p += __shfl_xor(p, off);
      q += __shfl_xor(q, off);
    }
    int row = rowbase + quad * 4 + r;
    if (l16 == 0 && row < N) {
      a_s[row] = p;
      a_d[row] = q;
    }
  }
}

// H=1, quarter-wave edge grouping (h2 natural layout).
__global__ void gat_agg1_kernel(const int* __restrict__ rowptr,
                                const int* __restrict__ col,
                                const float* __restrict__ a_s,
                                const float* __restrict__ a_d,
                                const unsigned short* __restrict__ hfeat,
                                const float* __restrict__ bias,
                                unsigned short* __restrict__ out, int N) {
  int wave = threadIdx.x >> 6, lane = threadIdx.x & 63;
  int d = blockIdx.x * 4 + wave;
  if (d >= N) return;
  int beg = rowptr[d], end = rowptr[d + 1];
  int qg = lane >> 4, l16 = lane & 15;
  float adv = a_d[d];
  const uint2* hfu = (const uint2*)hfeat;
  float acc[4] = {};
  float wsum = 0.f;
#pragma unroll 2
  for (int i = beg + qg; i < end; i += 4) {
    int s = col[i] & SMASK;
    float v = a_s[s] + adv;
    v = v > 0.f ? v : NEG * v;
    float wv = __expf(v);
    wsum += wv;
    uint2 u = hfu[(size_t)s * 16 + l16];
    acc[0] += wv * blo(u.x); acc[1] += wv * bhi(u.x);
    acc[2] += wv * blo(u.y); acc[3] += wv * bhi(u.y);
  }
#pragma unroll
  for (int off = 16; off <= 32; off <<= 1) {
#pragma unroll
    for (int j = 0; j < 4; ++j) acc[j] += __shfl_xor(acc[j], off);
    wsum += __shfl_xor(wsum, off);
  }
  float winv = 1.f / (wsum + 1e-16f);
  float4 bb = ((const float4*)bias)[l16];
  float r0 = elu1(acc[0] * winv + bb.x), r1 = elu1(acc[1] * winv + bb.y);
  float r2 = elu1(acc[2] * winv + bb.z), r3 = elu1(acc[3] * winv + bb.w);
  if (qg == 0) {
    uint2 o; o.x = pack2(r0, r1); o.y = pack2(r2, r3);
    ((uint2*)out)[(size_t)d * 16 + l16] = o;
  }
}

// ---------- pooling: 16 nodes per wave ----------
__global__ void pool_kernel(const unsigned short* __restrict__ out2,
                            const int* __restrict__ batch,
                            float* __restrict__ pooled, int N) {
  int wave = threadIdx.x >> 6, lane = threadIdx.x & 63;
  int seg = blockIdx.x * 4 + wave;
  int start = seg * 16;
  if (start >= N) return;
  int end = min(start + 16, N);
  int cur = batch[start];
  float acc = 0.f;
  for (int n = start; n < end; ++n) {
    int bn = batch[n];
    if (bn != cur) {
      unsafeAtomicAdd(&pooled[cur * 64 + lane], acc);
      acc = 0.f; cur = bn;
    }
    acc += bu(out2[(size_t)n * 64 + lane]);
  }
  unsafeAtomicAdd(&pooled[cur * 64 + lane], acc);
}

// ---------- MLP head + log_softmax: one block (one wave) per graph ----------
__global__ void head_kernel(const float* __restrict__ pooled,
                            const float* __restrict__ lin1_w,
                            const float* __restrict__ lin1_b,
                            const float* __restrict__ lin2_w,
                            const float* __restrict__ lin2_b,
                            const void* __restrict__ x_raw,
                            void* __restrict__ outv) {
  __shared__ float P[C];
  __shared__ float Zs[C];
  __shared__ float Ls[K];
  __shared__ float lse_s;
  __shared__ int fl;
  int isbf = detect_dev(x_raw, &fl);
  int g = blockIdx.x, t = threadIdx.x;   // 64 threads
  P[t] = pooled[g * C + t];
  __syncthreads();
  float acc = lin1_b[t];
  for (int k = 0; k < C; ++k) acc += P[k] * lin1_w[k * C + t];
  Zs[t] = elu1(acc);
  __syncthreads();
  if (t < K) {
    float a = lin2_b[t];
    for (int k = 0; k < C; ++k) a += Zs[k] * lin2_w[k * K + t];
    Ls[t] = a;
  }
  __syncthreads();
  if (t == 0) {
    float mx = -1e30f;
    for (int c = 0; c < K; ++c) mx = fmaxf(mx, Ls[c]);
    float s = 0.f;
    for (int c = 0; c < K; ++c) s += __expf(Ls[c] - mx);
    lse_s = mx + __logf(s);
  }
  __syncthreads();
  if (t < K) {
    float val = Ls[t] - lse_s;
    if (isbf) ((__hip_bfloat16*)outv)[g * K + t] = __float2bfloat16(val);
    else      ((float*)outv)[g * K + t] = val;
  }
}

extern "C" void kernel_launch(void* const* d_in, const int* in_sizes, int n_in,
                              void* d_out, int out_size, void* d_ws, size_t ws_size,
                              hipStream_t stream) {
  const void* x_raw = d_in[0];
  const int*  ei    = (const int*)d_in[1];
  const int*  batch = (const int*)d_in[2];

  const int N    = in_sizes[2];
  const int E    = in_sizes[1] / 2;
  const int Etot = E + N;
  const int nb   = (N + 255) / 256;

  float* ws   = (float*)d_ws;
  size_t off  = 0;

  float* wts = ws + off; off += 6544;
  float* b1w  = wts + 1024;
  float* as2w = wts + 1536;
  float* ad2w = wts + 1600;
  float* b2w  = wts + 1664;
  float* l1w  = wts + 1728;
  float* l1b  = wts + 5824;
  float* l2w  = wts + 5888;
  float* l2b  = wts + 6528;

  unsigned short* xbf    = (unsigned short*)(ws + off); off += (size_t)N * 64;
  unsigned short* w1frag = (unsigned short*)(ws + off); off += 32768;
  unsigned short* w2frag = (unsigned short*)(ws + off); off += 16384;
  unsigned short* vfrag  = (unsigned short*)(ws + off); off += 1024;
  unsigned short* wedge  = (unsigned short*)(ws + off); off += (size_t)Etot * 4;
  unsigned short* out1bf = (unsigned short*)(ws + off); off += (size_t)N * 256;
  unsigned short* h2bf   = (unsigned short*)(ws + off); off += (size_t)N * 32;
  unsigned short* out2bf = (unsigned short*)(ws + off); off += (size_t)N * 32;
  float* as1  = ws + off; off += (size_t)N * H1;
  float* ad1  = ws + off; off += (size_t)N * H1;
  float* as2  = ws + off; off += (size_t)N;
  float* ad2  = ws + off; off += (size_t)N;
  float* pooled = ws + off; off += (size_t)B * C;

  int* ibase  = (int*)(ws + off);
  int* deg    = ibase;                 ibase += N;
  int* cursor = ibase;                 ibase += N;
  int* rowptr = ibase;                 ibase += N + 1;
  int* locals = ibase;                 ibase += N;
  int* bsum   = ibase;                 ibase += 256;
  int* col    = ibase;                 ibase += Etot;

  // ---- prep ----
  fused_prep_kernel<<<1024, 256, 0, stream>>>(
      x_raw, d_in[3], d_in[4], d_in[5], d_in[6], d_in[7], d_in[8], d_in[9],
      d_in[10], d_in[11], d_in[12], d_in[13], d_in[14],
      xbf, w1frag, w2frag, vfrag, wts, deg, pooled, in_sizes[0], N);

  // ---- fused: layer-1 attention scalars + degree count ----
  {
    int attBlocks = (N + 63) / 64;
    int degBlocks = (Etot + 255) / 256;
    deg_att_kernel<<<attBlocks + degBlocks, 256, 0, stream>>>(
        ei, E, Etot, deg, xbf, vfrag, as1, ad1, N, attBlocks);
  }

  // ---- CSR scans ----
  scan_block_kernel<<<nb, 256, 0, stream>>>(deg, locals, bsum, N);
  scan_finish_kernel<<<nb, 256, 0, stream>>>(locals, bsum, nb, rowptr, cursor, N, Etot);

  // ---- CSR fill + per-edge softmax weights (bf16) ----
  fill_weight_kernel<<<(Etot + 255) / 256, 256, 0, stream>>>(
      ei, E, Etot, as1, ad1, cursor, col, wedge);

  // ---- MFMA x-space aggregation + W1 GEMM -> out1 ----
  aggx_gemm1_kernel<<<(N + 15) / 16, 512, 0, stream>>>(
      xbf, w1frag, rowptr, col, wedge, b1w, out1bf, N);

  // ---- layer 2 ----
  gemm2_mfma_kernel<<<(N + 63) / 64, 256, 0, stream>>>(out1bf, w2frag, as2w, ad2w,
                                                       h2bf, as2, ad2, N);
  gat_agg1_kernel<<<(N + 3) / 4, 256, 0, stream>>>(rowptr, col, as2, ad2, h2bf, b2w, out2bf, N);

  // ---- pool + head ----
  pool_kernel<<<(N + 63) / 64, 256, 0, stream>>>(out2bf, batch, pooled, N);
  head_kernel<<<B, 64, 0, stream>>>(pooled, l1w, l1b, l2w, l2b, x_raw, (void*)d_out);
}

// Round 12
// 284.363 us; speedup vs baseline: 1.0288x; 1.0288x over previous
//
#include <hip/hip_runtime.h>
#include <hip/hip_bf16.h>

#define DEV static __device__ __forceinline__

constexpr int F1 = 128;   // input features
constexpr int H1 = 8;     // heads layer1
constexpr int C  = 64;    // channels per head
constexpr int B  = 64;    // graphs
constexpr int K  = 10;    // classes
constexpr float NEG = 0.2f;
constexpr unsigned SMASK = 0x07FFFFFFu;   // col[] low bits = src id; bits 27-30 = dest&15

typedef __attribute__((ext_vector_type(8))) short short8;
typedef __attribute__((ext_vector_type(4))) float floatx4;

DEV float b2f(__hip_bfloat16 x) { return __bfloat162float(x); }
DEV float elu1(float v) { return v > 0.f ? v : (__expf(v) - 1.f); }
DEV unsigned short f2bbits(float f) {
  __hip_bfloat16 b = __float2bfloat16(f);
  return *(unsigned short*)&b;
}
DEV float blo(unsigned u) { return __uint_as_float(u << 16); }
DEV float bhi(unsigned u) { return __uint_as_float(u & 0xffff0000u); }
DEV float bu(unsigned short u) { return __uint_as_float(((unsigned)u) << 16); }
DEV unsigned pack2(float lo, float hi) {
  return (unsigned)f2bbits(lo) | ((unsigned)f2bbits(hi) << 16);
}
// 1/x via v_rcp_f32 + one Newton step
DEV float rcp_nr(float x) {
  float r = __builtin_amdgcn_rcpf(x);
  return r * (2.f - x * r);
}

// out1 PERMUTED layout: position p = hp*128 + l16*8 + nt  <->  natural channel
// c = hp*128 + nt*16 + l16. W2frag k-rows and b1 permuted to match.
// W1frag k is NATURAL.

// Self-detection: thread 0 samples 128 even-index bf16 reinterps of x.
DEV int detect_dev(const void* xraw, int* lds) {
  if (threadIdx.x == 0) {
    const __hip_bfloat16* xb = (const __hip_bfloat16*)xraw;
    int bad = 0;
    for (int i = 0; i < 128; ++i) {
      float v = b2f(xb[2 * i]);
      if (!(fabsf(v) < 1e4f)) bad++;
    }
    *lds = (bad < 13) ? 1 : 0;     // 1 = bf16, 0 = f32
  }
  __syncthreads();
  return *lds;
}

#define CVT(p, i) (isbf ? b2f(((const __hip_bfloat16*)(p))[i]) : ((const float*)(p))[i])

// ---------- fused prep ----------
__global__ void fused_prep_kernel(const void* x_raw, const void* w1raw,
                                  const void* as1r, const void* ad1r, const void* b1r,
                                  const void* w2raw,
                                  const void* as2r, const void* ad2r, const void* b2r,
                                  const void* l1wr, const void* l1br,
                                  const void* l2wr, const void* l2br,
                                  unsigned short* __restrict__ xbf,
                                  unsigned short* __restrict__ w1frag,
                                  unsigned short* __restrict__ w2frag,
                                  unsigned short* __restrict__ vfrag,
                                  float* __restrict__ wts,
                                  int* __restrict__ deg,
                                  float* __restrict__ pooled,
                                  int nX, int N) {
  __shared__ int fl;
  int isbf = detect_dev(x_raw, &fl);
  int gid = blockIdx.x * 256 + threadIdx.x;
  int stride = gridDim.x * 256;

  // VECTORIZED xbf copy: 16B per thread-iteration (G13)
  int ng = nX >> 3;
  if (isbf) {
    const uint4* src = (const uint4*)x_raw;
    uint4* dst = (uint4*)xbf;
    for (int i = gid; i < ng; i += stride) dst[i] = src[i];
  } else {
    const float4* src = (const float4*)x_raw;
    uint4* dst = (uint4*)xbf;
    for (int i = gid; i < ng; i += stride) {
      float4 a = src[2 * i], b = src[2 * i + 1];
      uint4 o;
      o.x = pack2(a.x, a.y); o.y = pack2(a.z, a.w);
      o.z = pack2(b.x, b.y); o.w = pack2(b.z, b.w);
      dst[i] = o;
    }
  }
  for (int i = ng * 8 + gid; i < nX; i += stride)   // tail (nX%8, normally 0)
    xbf[i] = isbf ? ((const unsigned short*)x_raw)[i]
                  : f2bbits(((const float*)x_raw)[i]);

  // b1 stored PERMUTED: wts[1024 + p] = b1[c_nat(p)]
  for (int i = gid; i < 512;  i += stride) {
    int hp = i >> 7, l16 = (i >> 3) & 15, nt = i & 7;
    int c = hp * 128 + nt * 16 + l16;
    wts[1024 + i] = CVT(b1r, c);
  }
  for (int i = gid; i < 64;   i += stride) wts[1536 + i] = CVT(as2r, i);
  for (int i = gid; i < 64;   i += stride) wts[1600 + i] = CVT(ad2r, i);
  for (int i = gid; i < 64;   i += stride) wts[1664 + i] = CVT(b2r, i);
  for (int i = gid; i < 4096; i += stride) wts[1728 + i] = CVT(l1wr, i);
  for (int i = gid; i < 64;   i += stride) wts[5824 + i] = CVT(l1br, i);
  for (int i = gid; i < 640;  i += stride) wts[5888 + i] = CVT(l2wr, i);
  for (int i = gid; i < 10;   i += stride) wts[6528 + i] = CVT(l2br, i);
  // W1frag NATURAL k
  for (int t = gid; t < 8192; t += stride) {
    int lane = t & 63, ks = (t >> 6) & 3, nt = t >> 8;
    for (int j = 0; j < 8; ++j) {
      int k = ks * 32 + (lane >> 4) * 8 + j;
      int n = nt * 16 + (lane & 15);
      w1frag[t * 8 + j] = f2bbits(CVT(w1raw, k * 512 + n));
    }
  }
  // W2frag with PERMUTED k: k index in fragment = position p; fetch W2[c_nat(p)]
  for (int t = gid; t < 4096; t += stride) {
    int lane = t & 63, nt = (t >> 6) & 3, ks = t >> 8;
    for (int j = 0; j < 8; ++j) {
      int p = ks * 32 + (lane >> 4) * 8 + j;          // permuted position
      int hp = p >> 7, pl16 = (p >> 3) & 15, pnt = p & 7;
      int k = hp * 128 + pnt * 16 + pl16;             // natural channel
      int n = nt * 16 + (lane & 15);
      w2frag[t * 8 + j] = f2bbits(CVT(w2raw, k * 64 + n));
    }
  }
  // Vfrag: B-fragment of V[128 x 16], V[:,n<8] = W1 head-n col @ att_src[n],
  // V[:,n>=8] = same with att_dst. a_s/a_d = x @ V.
  for (int t = gid; t < 2048; t += stride) {
    int j = t & 7, lane = (t >> 3) & 63, ks = t >> 9;
    int k = ks * 32 + (lane >> 4) * 8 + j;
    int n = lane & 15;
    int hh = (n < 8) ? n : (n - 8);
    float s = 0.f;
    if (n < 8) {
      for (int c = 0; c < 64; ++c)
        s += CVT(w1raw, k * 512 + hh * 64 + c) * CVT(as1r, hh * 64 + c);
    } else {
      for (int c = 0; c < 64; ++c)
        s += CVT(w1raw, k * 512 + hh * 64 + c) * CVT(ad1r, hh * 64 + c);
    }
    vfrag[(ks * 64 + lane) * 8 + j] = f2bbits(s);
  }
  for (int i = gid; i < N; i += stride) deg[i] = 0;
  for (int i = gid; i < B * C; i += stride) pooled[i] = 0.f;
}

// ---------- FUSED: att_scalars (blocks < attBlocks) + degree count ----------
__global__ __launch_bounds__(256) void deg_att_kernel(
    const int* __restrict__ ei, int E, int Etot, int* __restrict__ deg,
    const unsigned short* __restrict__ xbf,     // N x 128 bf16
    const unsigned short* __restrict__ vfrag,   // [4ks][64][8] bf16
    float* __restrict__ a_s, float* __restrict__ a_d,   // N x 8
    int N, int attBlocks) {
  if ((int)blockIdx.x >= attBlocks) {
    int e = ((int)blockIdx.x - attBlocks) * 256 + threadIdx.x;
    if (e < Etot) {
      int d = (e < E) ? ei[E + e] : e - E;
      atomicAdd(&deg[d], 1);
    }
    return;
  }
  int t = threadIdx.x, w = t >> 6, lane = t & 63;
  int quad = lane >> 4, l16 = lane & 15;
  int row0 = blockIdx.x * 64 + w * 16;

  floatx4 acc = {};
  int rl = row0 + l16; if (rl >= N) rl = N - 1;
  const unsigned short* xp = xbf + (size_t)rl * 128 + quad * 8;
#pragma unroll
  for (int ks = 0; ks < 4; ++ks) {
    short8 a = *(const short8*)(xp + ks * 32);
    short8 b = *(const short8*)&vfrag[(ks * 64 + lane) * 8];
    acc = __builtin_amdgcn_mfma_f32_16x16x32_bf16(a, b, acc, 0, 0, 0);
  }
#pragma unroll
  for (int r = 0; r < 4; ++r) {
    int row = row0 + quad * 4 + r;
    if (row < N) {
      if (l16 < 8) a_s[(size_t)row * 8 + l16] = acc[r];
      else         a_d[(size_t)row * 8 + (l16 - 8)] = acc[r];
    }
  }
}

// ---------- CSR scans ----------
__global__ void scan_block_kernel(const int* __restrict__ deg,
                                  int* __restrict__ local,
                                  int* __restrict__ bsum, int N) {
  __shared__ int tmp[256];
  int t = threadIdx.x;
  int i = blockIdx.x * 256 + t;
  int v = (i < N) ? deg[i] : 0;
  tmp[t] = v;
  __syncthreads();
  for (int off = 1; off < 256; off <<= 1) {
    int u = (t >= off) ? tmp[t - off] : 0;
    __syncthreads();
    tmp[t] += u;
    __syncthreads();
  }
  if (i < N) local[i] = tmp[t] - v;
  if (t == 255) bsum[blockIdx.x] = tmp[255];
}

__global__ void scan_finish_kernel(const int* __restrict__ local,
                                   const int* __restrict__ bsum, int nb,
                                   int* __restrict__ rowptr,
                                   int* __restrict__ cursor, int N, int Etot) {
  __shared__ int tmp[256];
  __shared__ int offs;
  int t = threadIdx.x;
  int v0 = (t < nb) ? bsum[t] : 0;
  tmp[t] = v0;
  __syncthreads();
  for (int off = 1; off < 256; off <<= 1) {
    int u = (t >= off) ? tmp[t - off] : 0;
    __syncthreads();
    tmp[t] += u;
    __syncthreads();
  }
  if (t == (int)blockIdx.x) offs = tmp[t] - v0;
  __syncthreads();
  int i = blockIdx.x * 256 + t;
  if (i < N) {
    int r = local[i] + offs;
    rowptr[i] = r;
    cursor[i] = r;
  }
  if (i == 0) rowptr[N] = Etot;
}

// ---------- CSR fill + per-edge softmax weights (bf16 x8, CSR slot order) ----
// col[pos] = src | (dest&15)<<27. No hot-address atomics (round-7 lesson).
__global__ void fill_weight_kernel(const int* __restrict__ ei, int E, int Etot,
                                   const float* __restrict__ a_s,
                                   const float* __restrict__ a_d,
                                   int* __restrict__ cursor,
                                   int* __restrict__ col,
                                   unsigned short* __restrict__ wedge) {
  int e = blockIdx.x * 256 + threadIdx.x;
  if (e >= Etot) return;
  int s, d;
  if (e < E) { s = ei[e]; d = ei[E + e]; } else { s = d = e - E; }
  int pos = atomicAdd(&cursor[d], 1);
  col[pos] = s | ((d & 15) << 27);
  float4 s0 = *(const float4*)(a_s + (size_t)s * 8);
  float4 s1 = *(const float4*)(a_s + (size_t)s * 8 + 4);
  float4 d0 = *(const float4*)(a_d + (size_t)d * 8);
  float4 d1 = *(const float4*)(a_d + (size_t)d * 8 + 4);
  float v, w0, w1, w2, w3, w4, w5, w6, w7;
  v = s0.x + d0.x; v = v > 0.f ? v : NEG * v; w0 = __expf(v);
  v = s0.y + d0.y; v = v > 0.f ? v : NEG * v; w1 = __expf(v);
  v = s0.z + d0.z; v = v > 0.f ? v : NEG * v; w2 = __expf(v);
  v = s0.w + d0.w; v = v > 0.f ? v : NEG * v; w3 = __expf(v);
  v = s1.x + d1.x; v = v > 0.f ? v : NEG * v; w4 = __expf(v);
  v = s1.y + d1.y; v = v > 0.f ? v : NEG * v; w5 = __expf(v);
  v = s1.z + d1.z; v = v > 0.f ? v : NEG * v; w6 = __expf(v);
  v = s1.w + d1.w; v = v > 0.f ? v : NEG * v; w7 = __expf(v);
  uint4 o;
  o.x = pack2(w0, w1); o.y = pack2(w2, w3);
  o.z = pack2(w4, w5); o.w = pack2(w6, w7);
  *(uint4*)(wedge + (size_t)pos * 8) = o;
}

// ---------- MFMA-based x-space aggregation + W1 GEMM -> out1 ----------
// ROUND-9 OPTIMUM restored (chunk=64 regressed: occupancy 51->37%, conflicts
// 7.9M->9.2M). Block = 512 threads (8 waves), TILE = 16 dests, chunks of 32
// edge slots. Pipelined (T14): write prefetched regs -> buf[c&1], issue chunk
// c+1 loads, ONE barrier, 9 MFMA. LDS: 2 x 16K dbuf UNION AggP 34.8K.
__global__ __launch_bounds__(512, 6) void aggx_gemm1_kernel(
    const unsigned short* __restrict__ xbf,     // N x 128 bf16
    const unsigned short* __restrict__ W1frag,  // [32][4][64][8] bf16 (natural k)
    const int* __restrict__ rowptr,
    const int* __restrict__ col,                // src | dl<<27
    const unsigned short* __restrict__ wedge,   // Etot x 8 bf16 (CSR order)
    const float* __restrict__ bias_perm,        // 512, PERMUTED
    unsigned short* __restrict__ out1,          // N x 512 bf16 (PERMUTED)
    int N) {
  __shared__ __align__(16) char LB[8 * 16 * 136 * 2];   // 34816 B union
  unsigned short* AggP = (unsigned short*)LB;           // 34.8 KB (epilogue)

  int t = threadIdx.x, w = t >> 6, lane = t & 63;
  int q = lane >> 4, n = lane & 15;
  int dbase = blockIdx.x * 16;

  int R0 = rowptr[dbase];
  int R1 = rowptr[min(dbase + 16, N)];
  int nch = (R1 - R0 + 31) >> 5;

  // staging ids: kp = edge-pair (0..15), pp = feature-quad (0..31)
  int kp = t >> 5, pp = t & 31;
  int skey = (pp & 7) << 4;              // = ((f>>2)&7)<<4 for f = 4*pp+df
  // wmat ids
  int dw = t >> 5, kw = t & 31;

  // ones B-fragment: B[k][n] = (n==0) ? 1.0bf16 : 0
  short8 onesf = {};
  if (n == 0) {
#pragma unroll
    for (int j = 0; j < 8; ++j) onesf[j] = (short)0x3F80;
  }

  floatx4 accw[8] = {};
  floatx4 accdn = {};

  // prefetched chunk data
  uint2 pxa, pxb;
  uint4 pwv;
  int pcv;
  {
    int e0 = R0 + 2 * kp;
    int ec0 = min(e0, R1 - 1), ec1 = min(e0 + 1, R1 - 1);
    int s0 = col[ec0] & SMASK;
    int s1 = col[ec1] & SMASK;
    pxa = *(const uint2*)(xbf + (size_t)s0 * 128 + pp * 4);
    pxb = *(const uint2*)(xbf + (size_t)s1 * 128 + pp * 4);
    int ew = min(R0 + kw, R1 - 1);
    pcv = col[ew];
    pwv = *(const uint4*)(wedge + (size_t)ew * 8);
  }

  for (int c = 0; c < nch; ++c) {
    char* Lb = LB + (c & 1) * 16384;
    unsigned short* XgTc = (unsigned short*)Lb;
    unsigned short* Wmc  = (unsigned short*)(Lb + 8192);

    // ---- phase A: write prefetched chunk c into buf[c&1] ----
    {
      int base = 256 * pp + 4 * kp;
      unsigned w0 = (pxa.x & 0xffffu) | (pxb.x << 16);
      unsigned w1 = (pxa.x >> 16) | (pxb.x & 0xffff0000u);
      unsigned w2 = (pxa.y & 0xffffu) | (pxb.y << 16);
      unsigned w3 = (pxa.y >> 16) | (pxb.y & 0xffff0000u);
      *(unsigned*)(Lb + ((base)       ^ skey)) = w0;
      *(unsigned*)(Lb + ((base + 64)  ^ skey)) = w1;
      *(unsigned*)(Lb + ((base + 128) ^ skey)) = w2;
      *(unsigned*)(Lb + ((base + 192) ^ skey)) = w3;

      int ew = R0 + c * 32 + kw;
      int dl = (pcv >> 27) & 15;
      bool mine = (ew < R1) && (dl == dw);
      unsigned short* wmp = Wmc + dw * 32 + kw;
      wmp[0]    = mine ? (unsigned short)(pwv.x & 0xffff) : 0;
      wmp[512]  = mine ? (unsigned short)(pwv.x >> 16)    : 0;
      wmp[1024] = mine ? (unsigned short)(pwv.y & 0xffff) : 0;
      wmp[1536] = mine ? (unsigned short)(pwv.y >> 16)    : 0;
      wmp[2048] = mine ? (unsigned short)(pwv.z & 0xffff) : 0;
      wmp[2560] = mine ? (unsigned short)(pwv.z >> 16)    : 0;
      wmp[3072] = mine ? (unsigned short)(pwv.w & 0xffff) : 0;
      wmp[3584] = mine ? (unsigned short)(pwv.w >> 16)    : 0;
    }
    // ---- phase B: issue chunk c+1 loads (latency hides under MFMA) ----
    if (c + 1 < nch) {
      int ebase = R0 + (c + 1) * 32;
      int e0 = ebase + 2 * kp;
      int ec0 = min(e0, R1 - 1), ec1 = min(e0 + 1, R1 - 1);
      int s0 = col[ec0] & SMASK;
      int s1 = col[ec1] & SMASK;
      pxa = *(const uint2*)(xbf + (size_t)s0 * 128 + pp * 4);
      pxb = *(const uint2*)(xbf + (size_t)s1 * 128 + pp * 4);
      int ew = min(ebase + kw, R1 - 1);
      pcv = col[ew];
      pwv = *(const uint4*)(wedge + (size_t)ew * 8);
    }
    __syncthreads();

    // ---- phase C: MFMA from buf[c&1]; wave w = head w ----
    short8 af = *(const short8*)(Wmc + w * 512 + n * 32 + 8 * q);
    accdn = __builtin_amdgcn_mfma_f32_16x16x32_bf16(af, onesf, accdn, 0, 0, 0);
#pragma unroll
    for (int ft = 0; ft < 8; ++ft) {
      int f = ft * 16 + n;
      int bb = f * 64 + 16 * q;
      bb ^= ((f >> 2) & 7) << 4;
      short8 bfr = *(const short8*)((const char*)XgTc + bb);
      accw[ft] = __builtin_amdgcn_mfma_f32_16x16x32_bf16(af, bfr, accw[ft], 0, 0, 0);
    }
  }

  __syncthreads();                         // last MFMA reads done before AggP

  // ---- epilogue: normalize (denominator from accdn col 0), write AggP ----
  {
    float dnv[4];
#pragma unroll
    for (int r = 0; r < 4; ++r) {
      float dr = __shfl(accdn[r], lane & 48);      // broadcast col-0 lane of quad
      dnv[r] = rcp_nr(dr + 1e-16f);
    }
#pragma unroll
    for (int ft = 0; ft < 8; ++ft)
#pragma unroll
      for (int r = 0; r < 4; ++r)
        AggP[w * 2176 + (4 * q + r) * 136 + ft * 16 + n] =
            f2bbits(accw[ft][r] * dnv[r]);
  }
  __syncthreads();

  // ---- phase 3: per-head W1 GEMM, bias + ELU, permuted store ----
  {
    int hp = w >> 1, qq = w & 1;
    floatx4 acc2[4] = {};
    const unsigned short* Bp = W1frag + (size_t)hp * 16384;
#pragma unroll
    for (int ks = 0; ks < 4; ++ks) {
      short8 a2 = *(const short8*)&AggP[w * 2176 + n * 136 + ks * 32 + q * 8];
#pragma unroll
      for (int j = 0; j < 4; ++j) {
        int nt = qq * 4 + j;
        short8 b2 = *(const short8*)&Bp[((nt * 4 + ks) * 64 + lane) * 8];
        acc2[j] = __builtin_amdgcn_mfma_f32_16x16x32_bf16(a2, b2, acc2[j], 0, 0, 0);
      }
    }
    float4 bq = *(const float4*)&bias_perm[hp * 128 + n * 8 + qq * 4];
#pragma unroll
    for (int r = 0; r < 4; ++r) {
      int row = dbase + 4 * q + r;
      if (row < N) {
        uint2 o;
        o.x = pack2(elu1(acc2[0][r] + bq.x), elu1(acc2[1][r] + bq.y));
        o.y = pack2(elu1(acc2[2][r] + bq.z), elu1(acc2[3][r] + bq.w));
        *(uint2*)&out1[(size_t)row * 512 + hp * 128 + n * 8 + qq * 4] = o;
      }
    }
  }
}

// ---------- layer 2: MFMA bf16 GEMM (k-dim permuted to match out1bf) ----------
__global__ __launch_bounds__(256) void gemm2_mfma_kernel(
    const unsigned short* __restrict__ x2bf,    // N x 512 bf16 (PERMUTED k)
    const unsigned short* __restrict__ W2frag,  // [16ks][4nt][64][8] bf16 (perm k)
    const float* __restrict__ att_src,          // 64
    const float* __restrict__ att_dst,
    unsigned short* __restrict__ h2,            // N x 64 bf16 (natural)
    float* __restrict__ a_s, float* __restrict__ a_d,  // N
    int N) {
  int t = threadIdx.x;
  int w = t >> 6, lane = t & 63;
  int quad = lane >> 4, l16 = lane & 15;
  int rowbase = blockIdx.x * 64 + w * 16;

  floatx4 acc[4] = {};
  int r0 = rowbase + l16; if (r0 >= N) r0 = N - 1;
  const unsigned short* p0 = x2bf + (size_t)r0 * 512 + quad * 8;
#pragma unroll
  for (int ks = 0; ks < 16; ++ks) {
    short8 a0 = *(const short8*)(p0 + ks * 32);
#pragma unroll
    for (int nt = 0; nt < 4; ++nt) {
      short8 b = *(const short8*)&W2frag[((ks * 4 + nt) * 64 + lane) * 8];
      acc[nt] = __builtin_amdgcn_mfma_f32_16x16x32_bf16(a0, b, acc[nt], 0, 0, 0);
    }
  }

  float asw[4], adw[4];
#pragma unroll
  for (int nt = 0; nt < 4; ++nt) {
    asw[nt] = att_src[nt * 16 + l16];
    adw[nt] = att_dst[nt * 16 + l16];
  }
  float ps[4] = {}, pd[4] = {};
#pragma unroll
  for (int nt = 0; nt < 4; ++nt)
#pragma unroll
    for (int r = 0; r < 4; ++r) {
      float v = acc[nt][r];
      int row = rowbase + quad * 4 + r;
      if (row < N) h2[(size_t)row * 64 + nt * 16 + l16] = f2bbits(v);
      ps[r] += v * asw[nt];
      pd[r] += v * adw[nt];
    }
#pragma unroll
  for (int r = 0; r < 4; ++r) {
    float p = ps[r], q = pd[r];
#pragma unroll
    for (int off = 1; off < 16; off <<= 1) {
      p += __shfl_xor(p, off);
      q += __shfl_xor(q, off);
    }
    int row = rowbase + quad * 4 + r;
    if (l16 == 0 && row < N) {
      a_s[row] = p;
      a_d[row] = q;
    }
  }
}

// H=1, quarter-wave edge grouping (h2 natural layout).
__global__ void gat_agg1_kernel(const int* __restrict__ rowptr,
                                const int* __restrict__ col,
                                const float* __restrict__ a_s,
                                const float* __restrict__ a_d,
                                const unsigned short* __restrict__ hfeat,
                                const float* __restrict__ bias,
                                unsigned short* __restrict__ out, int N) {
  int wave = threadIdx.x >> 6, lane = threadIdx.x & 63;
  int d = blockIdx.x * 4 + wave;
  if (d >= N) return;
  int beg = rowptr[d], end = rowptr[d + 1];
  int qg = lane >> 4, l16 = lane & 15;
  float adv = a_d[d];
  const uint2* hfu = (const uint2*)hfeat;
  float acc[4] = {};
  float wsum = 0.f;
#pragma unroll 2
  for (int i = beg + qg; i < end; i += 4) {
    int s = col[i] & SMASK;
    float v = a_s[s] + adv;
    v = v > 0.f ? v : NEG * v;
    float wv = __expf(v);
    wsum += wv;
    uint2 u = hfu[(size_t)s * 16 + l16];
    acc[0] += wv * blo(u.x); acc[1] += wv * bhi(u.x);
    acc[2] += wv * blo(u.y); acc[3] += wv * bhi(u.y);
  }
#pragma unroll
  for (int off = 16; off <= 32; off <<= 1) {
#pragma unroll
    for (int j = 0; j < 4; ++j) acc[j] += __shfl_xor(acc[j], off);
    wsum += __shfl_xor(wsum, off);
  }
  float winv = 1.f / (wsum + 1e-16f);
  float4 bb = ((const float4*)bias)[l16];
  float r0 = elu1(acc[0] * winv + bb.x), r1 = elu1(acc[1] * winv + bb.y);
  float r2 = elu1(acc[2] * winv + bb.z), r3 = elu1(acc[3] * winv + bb.w);
  if (qg == 0) {
    uint2 o; o.x = pack2(r0, r1); o.y = pack2(r2, r3);
    ((uint2*)out)[(size_t)d * 16 + l16] = o;
  }
}

// ---------- pooling: 16 nodes per wave ----------
__global__ void pool_kernel(const unsigned short* __restrict__ out2,
                            const int* __restrict__ batch,
                            float* __restrict__ pooled, int N) {
  int wave = threadIdx.x >> 6, lane = threadIdx.x & 63;
  int seg = blockIdx.x * 4 + wave;
  int start = seg * 16;
  if (start >= N) return;
  int end = min(start + 16, N);
  int cur = batch[start];
  float acc = 0.f;
  for (int n = start; n < end; ++n) {
    int bn = batch[n];
    if (bn != cur) {
      unsafeAtomicAdd(&pooled[cur * 64 + lane], acc);
      acc = 0.f; cur = bn;
    }
    acc += bu(out2[(size_t)n * 64 + lane]);
  }
  unsafeAtomicAdd(&pooled[cur * 64 + lane], acc);
}

// ---------- MLP head + log_softmax: one block (one wave) per graph ----------
__global__ void head_kernel(const float* __restrict__ pooled,
                            const float* __restrict__ lin1_w,
                            const float* __restrict__ lin1_b,
                            const float* __restrict__ lin2_w,
                            const float* __restrict__ lin2_b,
                            const void* __restrict__ x_raw,
                            void* __restrict__ outv) {
  __shared__ float P[C];
  __shared__ float Zs[C];
  __shared__ float Ls[K];
  __shared__ float lse_s;
  __shared__ int fl;
  int isbf = detect_dev(x_raw, &fl);
  int g = blockIdx.x, t = threadIdx.x;   // 64 threads
  P[t] = pooled[g * C + t];
  __syncthreads();
  float acc = lin1_b[t];
  for (int k = 0; k < C; ++k) acc += P[k] * lin1_w[k * C + t];
  Zs[t] = elu1(acc);
  __syncthreads();
  if (t < K) {
    float a = lin2_b[t];
    for (int k = 0; k < C; ++k) a += Zs[k] * lin2_w[k * K + t];
    Ls[t] = a;
  }
  __syncthreads();
  if (t == 0) {
    float mx = -1e30f;
    for (int c = 0; c < K; ++c) mx = fmaxf(mx, Ls[c]);
    float s = 0.f;
    for (int c = 0; c < K; ++c) s += __expf(Ls[c] - mx);
    lse_s = mx + __logf(s);
  }
  __syncthreads();
  if (t < K) {
    float val = Ls[t] - lse_s;
    if (isbf) ((__hip_bfloat16*)outv)[g * K + t] = __float2bfloat16(val);
    else      ((float*)outv)[g * K + t] = val;
  }
}

extern "C" void kernel_launch(void* const* d_in, const int* in_sizes, int n_in,
                              void* d_out, int out_size, void* d_ws, size_t ws_size,
                              hipStream_t stream) {
  const void* x_raw = d_in[0];
  const int*  ei    = (const int*)d_in[1];
  const int*  batch = (const int*)d_in[2];

  const int N    = in_sizes[2];
  const int E    = in_sizes[1] / 2;
  const int Etot = E + N;
  const int nb   = (N + 255) / 256;

  float* ws   = (float*)d_ws;
  size_t off  = 0;

  float* wts = ws + off; off += 6544;
  float* b1w  = wts + 1024;
  float* as2w = wts + 1536;
  float* ad2w = wts + 1600;
  float* b2w  = wts + 1664;
  float* l1w  = wts + 1728;
  float* l1b  = wts + 5824;
  float* l2w  = wts + 5888;
  float* l2b  = wts + 6528;

  unsigned short* xbf    = (unsigned short*)(ws + off); off += (size_t)N * 64;
  unsigned short* w1frag = (unsigned short*)(ws + off); off += 32768;
  unsigned short* w2frag = (unsigned short*)(ws + off); off += 16384;
  unsigned short* vfrag  = (unsigned short*)(ws + off); off += 1024;
  unsigned short* wedge  = (unsigned short*)(ws + off); off += (size_t)Etot * 4;
  unsigned short* out1bf = (unsigned short*)(ws + off); off += (size_t)N * 256;
  unsigned short* h2bf   = (unsigned short*)(ws + off); off += (size_t)N * 32;
  unsigned short* out2bf = (unsigned short*)(ws + off); off += (size_t)N * 32;
  float* as1  = ws + off; off += (size_t)N * H1;
  float* ad1  = ws + off; off += (size_t)N * H1;
  float* as2  = ws + off; off += (size_t)N;
  float* ad2  = ws + off; off += (size_t)N;
  float* pooled = ws + off; off += (size_t)B * C;

  int* ibase  = (int*)(ws + off);
  int* deg    = ibase;                 ibase += N;
  int* cursor = ibase;                 ibase += N;
  int* rowptr = ibase;                 ibase += N + 1;
  int* locals = ibase;                 ibase += N;
  int* bsum   = ibase;                 ibase += 256;
  int* col    = ibase;                 ibase += Etot;

  // ---- prep ----
  fused_prep_kernel<<<1024, 256, 0, stream>>>(
      x_raw, d_in[3], d_in[4], d_in[5], d_in[6], d_in[7], d_in[8], d_in[9],
      d_in[10], d_in[11], d_in[12], d_in[13], d_in[14],
      xbf, w1frag, w2frag, vfrag, wts, deg, pooled, in_sizes[0], N);

  // ---- fused: layer-1 attention scalars + degree count ----
  {
    int attBlocks = (N + 63) / 64;
    int degBlocks = (Etot + 255) / 256;
    deg_att_kernel<<<attBlocks + degBlocks, 256, 0, stream>>>(
        ei, E, Etot, deg, xbf, vfrag, as1, ad1, N, attBlocks);
  }

  // ---- CSR scans ----
  scan_block_kernel<<<nb, 256, 0, stream>>>(deg, locals, bsum, N);
  scan_finish_kernel<<<nb, 256, 0, stream>>>(locals, bsum, nb, rowptr, cursor, N, Etot);

  // ---- CSR fill + per-edge softmax weights (bf16) ----
  fill_weight_kernel<<<(Etot + 255) / 256, 256, 0, stream>>>(
      ei, E, Etot, as1, ad1, cursor, col, wedge);

  // ---- MFMA x-space aggregation + W1 GEMM -> out1 ----
  aggx_gemm1_kernel<<<(N + 15) / 16, 512, 0, stream>>>(
      xbf, w1frag, rowptr, col, wedge, b1w, out1bf, N);

  // ---- layer 2 ----
  gemm2_mfma_kernel<<<(N + 63) / 64, 256, 0, stream>>>(out1bf, w2frag, as2w, ad2w,
                                                       h2bf, as2, ad2, N);
  gat_agg1_kernel<<<(N + 3) / 4, 256, 0, stream>>>(rowptr, col, as2, ad2, h2bf, b2w, out2bf, N);

  // ---- pool + head ----
  pool_kernel<<<(N + 63) / 64, 256, 0, stream>>>(out2bf, batch, pooled, N);
  head_kernel<<<B, 64, 0, stream>>>(pooled, l1w, l1b, l2w, l2b, x_raw, (void*)d_out);
}

// Round 13
// 274.659 us; speedup vs baseline: 1.0652x; 1.0353x over previous
//
#include <hip/hip_runtime.h>
#include <hip/hip_bf16.h>

#define DEV static __device__ __forceinline__

constexpr int F1 = 128;   // input features
constexpr int H1 = 8;     // heads layer1
constexpr int C  = 64;    // channels per head
constexpr int B  = 64;    // graphs
constexpr int K  = 10;    // classes
constexpr float NEG = 0.2f;
constexpr unsigned SMASK = 0x07FFFFFFu;   // col[] low bits = src id; bits 27-30 = dest&15

typedef __attribute__((ext_vector_type(8))) short short8;
typedef __attribute__((ext_vector_type(4))) float floatx4;

DEV float b2f(__hip_bfloat16 x) { return __bfloat162float(x); }
DEV float elu1(float v) { return v > 0.f ? v : (__expf(v) - 1.f); }
DEV unsigned short f2bbits(float f) {
  __hip_bfloat16 b = __float2bfloat16(f);
  return *(unsigned short*)&b;
}
DEV float blo(unsigned u) { return __uint_as_float(u << 16); }
DEV float bhi(unsigned u) { return __uint_as_float(u & 0xffff0000u); }
DEV float bu(unsigned short u) { return __uint_as_float(((unsigned)u) << 16); }
DEV unsigned pack2(float lo, float hi) {
  return (unsigned)f2bbits(lo) | ((unsigned)f2bbits(hi) << 16);
}
// 1/x via v_rcp_f32 + one Newton step
DEV float rcp_nr(float x) {
  float r = __builtin_amdgcn_rcpf(x);
  return r * (2.f - x * r);
}

// out1 PERMUTED layout: position p = hp*128 + l16*8 + nt  <->  natural channel
// c = hp*128 + nt*16 + l16. W2frag k-rows and b1 permuted to match.
// W1frag k is NATURAL.

// Self-detection: thread 0 samples 128 even-index bf16 reinterps of x.
DEV int detect_dev(const void* xraw, int* lds) {
  if (threadIdx.x == 0) {
    const __hip_bfloat16* xb = (const __hip_bfloat16*)xraw;
    int bad = 0;
    for (int i = 0; i < 128; ++i) {
      float v = b2f(xb[2 * i]);
      if (!(fabsf(v) < 1e4f)) bad++;
    }
    *lds = (bad < 13) ? 1 : 0;     // 1 = bf16, 0 = f32
  }
  __syncthreads();
  return *lds;
}

#define CVT(p, i) (isbf ? b2f(((const __hip_bfloat16*)(p))[i]) : ((const float*)(p))[i])

// ---------- fused prep ----------
__global__ void fused_prep_kernel(const void* x_raw, const void* w1raw,
                                  const void* as1r, const void* ad1r, const void* b1r,
                                  const void* w2raw,
                                  const void* as2r, const void* ad2r, const void* b2r,
                                  const void* l1wr, const void* l1br,
                                  const void* l2wr, const void* l2br,
                                  unsigned short* __restrict__ xbf,
                                  unsigned short* __restrict__ w1frag,
                                  unsigned short* __restrict__ w2frag,
                                  unsigned short* __restrict__ vfrag,
                                  float* __restrict__ wts,
                                  int* __restrict__ deg,
                                  float* __restrict__ pooled,
                                  int nX, int N) {
  __shared__ int fl;
  int isbf = detect_dev(x_raw, &fl);
  int gid = blockIdx.x * 256 + threadIdx.x;
  int stride = gridDim.x * 256;

  // VECTORIZED xbf copy: 16B per thread-iteration (G13)
  int ng = nX >> 3;
  if (isbf) {
    const uint4* src = (const uint4*)x_raw;
    uint4* dst = (uint4*)xbf;
    for (int i = gid; i < ng; i += stride) dst[i] = src[i];
  } else {
    const float4* src = (const float4*)x_raw;
    uint4* dst = (uint4*)xbf;
    for (int i = gid; i < ng; i += stride) {
      float4 a = src[2 * i], b = src[2 * i + 1];
      uint4 o;
      o.x = pack2(a.x, a.y); o.y = pack2(a.z, a.w);
      o.z = pack2(b.x, b.y); o.w = pack2(b.z, b.w);
      dst[i] = o;
    }
  }
  for (int i = ng * 8 + gid; i < nX; i += stride)   // tail (nX%8, normally 0)
    xbf[i] = isbf ? ((const unsigned short*)x_raw)[i]
                  : f2bbits(((const float*)x_raw)[i]);

  // b1 stored PERMUTED: wts[1024 + p] = b1[c_nat(p)]
  for (int i = gid; i < 512;  i += stride) {
    int hp = i >> 7, l16 = (i >> 3) & 15, nt = i & 7;
    int c = hp * 128 + nt * 16 + l16;
    wts[1024 + i] = CVT(b1r, c);
  }
  for (int i = gid; i < 64;   i += stride) wts[1536 + i] = CVT(as2r, i);
  for (int i = gid; i < 64;   i += stride) wts[1600 + i] = CVT(ad2r, i);
  for (int i = gid; i < 64;   i += stride) wts[1664 + i] = CVT(b2r, i);
  for (int i = gid; i < 4096; i += stride) wts[1728 + i] = CVT(l1wr, i);
  for (int i = gid; i < 64;   i += stride) wts[5824 + i] = CVT(l1br, i);
  for (int i = gid; i < 640;  i += stride) wts[5888 + i] = CVT(l2wr, i);
  for (int i = gid; i < 10;   i += stride) wts[6528 + i] = CVT(l2br, i);
  // W1frag NATURAL k
  for (int t = gid; t < 8192; t += stride) {
    int lane = t & 63, ks = (t >> 6) & 3, nt = t >> 8;
    for (int j = 0; j < 8; ++j) {
      int k = ks * 32 + (lane >> 4) * 8 + j;
      int n = nt * 16 + (lane & 15);
      w1frag[t * 8 + j] = f2bbits(CVT(w1raw, k * 512 + n));
    }
  }
  // W2frag with PERMUTED k: k index in fragment = position p; fetch W2[c_nat(p)]
  for (int t = gid; t < 4096; t += stride) {
    int lane = t & 63, nt = (t >> 6) & 3, ks = t >> 8;
    for (int j = 0; j < 8; ++j) {
      int p = ks * 32 + (lane >> 4) * 8 + j;          // permuted position
      int hp = p >> 7, pl16 = (p >> 3) & 15, pnt = p & 7;
      int k = hp * 128 + pnt * 16 + pl16;             // natural channel
      int n = nt * 16 + (lane & 15);
      w2frag[t * 8 + j] = f2bbits(CVT(w2raw, k * 64 + n));
    }
  }
  // Vfrag: B-fragment of V[128 x 16], V[:,n<8] = W1 head-n col @ att_src[n],
  // V[:,n>=8] = same with att_dst. a_s/a_d = x @ V.
  for (int t = gid; t < 2048; t += stride) {
    int j = t & 7, lane = (t >> 3) & 63, ks = t >> 9;
    int k = ks * 32 + (lane >> 4) * 8 + j;
    int n = lane & 15;
    int hh = (n < 8) ? n : (n - 8);
    float s = 0.f;
    if (n < 8) {
      for (int c = 0; c < 64; ++c)
        s += CVT(w1raw, k * 512 + hh * 64 + c) * CVT(as1r, hh * 64 + c);
    } else {
      for (int c = 0; c < 64; ++c)
        s += CVT(w1raw, k * 512 + hh * 64 + c) * CVT(ad1r, hh * 64 + c);
    }
    vfrag[(ks * 64 + lane) * 8 + j] = f2bbits(s);
  }
  for (int i = gid; i < N; i += stride) deg[i] = 0;
  for (int i = gid; i < B * C; i += stride) pooled[i] = 0.f;
}

// ---------- FUSED: att_scalars (blocks < attBlocks) + degree count ----------
__global__ __launch_bounds__(256) void deg_att_kernel(
    const int* __restrict__ ei, int E, int Etot, int* __restrict__ deg,
    const unsigned short* __restrict__ xbf,     // N x 128 bf16
    const unsigned short* __restrict__ vfrag,   // [4ks][64][8] bf16
    float* __restrict__ a_s, float* __restrict__ a_d,   // N x 8
    int N, int attBlocks) {
  if ((int)blockIdx.x >= attBlocks) {
    int e = ((int)blockIdx.x - attBlocks) * 256 + threadIdx.x;
    if (e < Etot) {
      int d = (e < E) ? ei[E + e] : e - E;
      atomicAdd(&deg[d], 1);
    }
    return;
  }
  int t = threadIdx.x, w = t >> 6, lane = t & 63;
  int quad = lane >> 4, l16 = lane & 15;
  int row0 = blockIdx.x * 64 + w * 16;

  floatx4 acc = {};
  int rl = row0 + l16; if (rl >= N) rl = N - 1;
  const unsigned short* xp = xbf + (size_t)rl * 128 + quad * 8;
#pragma unroll
  for (int ks = 0; ks < 4; ++ks) {
    short8 a = *(const short8*)(xp + ks * 32);
    short8 b = *(const short8*)&vfrag[(ks * 64 + lane) * 8];
    acc = __builtin_amdgcn_mfma_f32_16x16x32_bf16(a, b, acc, 0, 0, 0);
  }
#pragma unroll
  for (int r = 0; r < 4; ++r) {
    int row = row0 + quad * 4 + r;
    if (row < N) {
      if (l16 < 8) a_s[(size_t)row * 8 + l16] = acc[r];
      else         a_d[(size_t)row * 8 + (l16 - 8)] = acc[r];
    }
  }
}

// ---------- CSR scans ----------
__global__ void scan_block_kernel(const int* __restrict__ deg,
                                  int* __restrict__ local,
                                  int* __restrict__ bsum, int N) {
  __shared__ int tmp[256];
  int t = threadIdx.x;
  int i = blockIdx.x * 256 + t;
  int v = (i < N) ? deg[i] : 0;
  tmp[t] = v;
  __syncthreads();
  for (int off = 1; off < 256; off <<= 1) {
    int u = (t >= off) ? tmp[t - off] : 0;
    __syncthreads();
    tmp[t] += u;
    __syncthreads();
  }
  if (i < N) local[i] = tmp[t] - v;
  if (t == 255) bsum[blockIdx.x] = tmp[255];
}

__global__ void scan_finish_kernel(const int* __restrict__ local,
                                   const int* __restrict__ bsum, int nb,
                                   int* __restrict__ rowptr,
                                   int* __restrict__ cursor, int N, int Etot) {
  __shared__ int tmp[256];
  __shared__ int offs;
  int t = threadIdx.x;
  int v0 = (t < nb) ? bsum[t] : 0;
  tmp[t] = v0;
  __syncthreads();
  for (int off = 1; off < 256; off <<= 1) {
    int u = (t >= off) ? tmp[t - off] : 0;
    __syncthreads();
    tmp[t] += u;
    __syncthreads();
  }
  if (t == (int)blockIdx.x) offs = tmp[t] - v0;
  __syncthreads();
  int i = blockIdx.x * 256 + t;
  if (i < N) {
    int r = local[i] + offs;
    rowptr[i] = r;
    cursor[i] = r;
  }
  if (i == 0) rowptr[N] = Etot;
}

// ---------- CSR fill + per-edge softmax weights (bf16 x8, CSR slot order) ----
// col[pos] = src | (dest&15)<<27. No hot-address atomics (round-7 lesson).
__global__ void fill_weight_kernel(const int* __restrict__ ei, int E, int Etot,
                                   const float* __restrict__ a_s,
                                   const float* __restrict__ a_d,
                                   int* __restrict__ cursor,
                                   int* __restrict__ col,
                                   unsigned short* __restrict__ wedge) {
  int e = blockIdx.x * 256 + threadIdx.x;
  if (e >= Etot) return;
  int s, d;
  if (e < E) { s = ei[e]; d = ei[E + e]; } else { s = d = e - E; }
  int pos = atomicAdd(&cursor[d], 1);
  col[pos] = s | ((d & 15) << 27);
  float4 s0 = *(const float4*)(a_s + (size_t)s * 8);
  float4 s1 = *(const float4*)(a_s + (size_t)s * 8 + 4);
  float4 d0 = *(const float4*)(a_d + (size_t)d * 8);
  float4 d1 = *(const float4*)(a_d + (size_t)d * 8 + 4);
  float v, w0, w1, w2, w3, w4, w5, w6, w7;
  v = s0.x + d0.x; v = v > 0.f ? v : NEG * v; w0 = __expf(v);
  v = s0.y + d0.y; v = v > 0.f ? v : NEG * v; w1 = __expf(v);
  v = s0.z + d0.z; v = v > 0.f ? v : NEG * v; w2 = __expf(v);
  v = s0.w + d0.w; v = v > 0.f ? v : NEG * v; w3 = __expf(v);
  v = s1.x + d1.x; v = v > 0.f ? v : NEG * v; w4 = __expf(v);
  v = s1.y + d1.y; v = v > 0.f ? v : NEG * v; w5 = __expf(v);
  v = s1.z + d1.z; v = v > 0.f ? v : NEG * v; w6 = __expf(v);
  v = s1.w + d1.w; v = v > 0.f ? v : NEG * v; w7 = __expf(v);
  uint4 o;
  o.x = pack2(w0, w1); o.y = pack2(w2, w3);
  o.z = pack2(w4, w5); o.w = pack2(w6, w7);
  *(uint4*)(wedge + (size_t)pos * 8) = o;
}

// ---------- MFMA x-space aggregation + W1 GEMM + FUSED layer-2 GEMM ----------
// Chunk loop identical to round-12 optimum (chunk=32, T14 pipeline, (512,6)).
// Epilogue fusion: out1 never hits global. Phase 3a computes out1 values in
// registers (acc2); they're staged to LDS O1[16][520] (bias+ELU applied), then
// phase 3b runs the [16x512]@[512x64] W2 GEMM in-block: wave -> (nt=w&3,
// K-half=w>>2), K-halves reduced via LDS, h2 + attention scalars stored.
// Saves 25.6MB out1 write + 25.6MB gemm2 re-read + one dispatch.
__global__ __launch_bounds__(512, 6) void aggx_gemm12_kernel(
    const unsigned short* __restrict__ xbf,     // N x 128 bf16
    const unsigned short* __restrict__ W1frag,  // [32][4][64][8] bf16 (natural k)
    const int* __restrict__ rowptr,
    const int* __restrict__ col,                // src | dl<<27
    const unsigned short* __restrict__ wedge,   // Etot x 8 bf16 (CSR order)
    const float* __restrict__ bias_perm,        // 512, PERMUTED
    const unsigned short* __restrict__ W2frag,  // [16ks][4nt][64][8] bf16 (perm k)
    const float* __restrict__ att_src2,         // 64
    const float* __restrict__ att_dst2,
    unsigned short* __restrict__ h2,            // N x 64 bf16 (natural)
    float* __restrict__ a_s2, float* __restrict__ a_d2,  // N
    int N) {
  __shared__ __align__(16) char LB[8 * 16 * 136 * 2];   // 34816 B, multi-role

  int t = threadIdx.x, w = t >> 6, lane = t & 63;
  int q = lane >> 4, n = lane & 15;
  int dbase = blockIdx.x * 16;

  int R0 = rowptr[dbase];
  int R1 = rowptr[min(dbase + 16, N)];
  int nch = (R1 - R0 + 31) >> 5;

  // staging ids: kp = edge-pair (0..15), pp = feature-quad (0..31)
  int kp = t >> 5, pp = t & 31;
  int skey = (pp & 7) << 4;              // = ((f>>2)&7)<<4 for f = 4*pp+df
  // wmat ids
  int dw = t >> 5, kw = t & 31;

  // ones B-fragment: B[k][n] = (n==0) ? 1.0bf16 : 0
  short8 onesf = {};
  if (n == 0) {
#pragma unroll
    for (int j = 0; j < 8; ++j) onesf[j] = (short)0x3F80;
  }

  floatx4 accw[8] = {};
  floatx4 accdn = {};

  // prefetched chunk data
  uint2 pxa, pxb;
  uint4 pwv;
  int pcv;
  {
    int e0 = R0 + 2 * kp;
    int ec0 = min(e0, R1 - 1), ec1 = min(e0 + 1, R1 - 1);
    int s0 = col[ec0] & SMASK;
    int s1 = col[ec1] & SMASK;
    pxa = *(const uint2*)(xbf + (size_t)s0 * 128 + pp * 4);
    pxb = *(const uint2*)(xbf + (size_t)s1 * 128 + pp * 4);
    int ew = min(R0 + kw, R1 - 1);
    pcv = col[ew];
    pwv = *(const uint4*)(wedge + (size_t)ew * 8);
  }

  for (int c = 0; c < nch; ++c) {
    char* Lb = LB + (c & 1) * 16384;
    unsigned short* XgTc = (unsigned short*)Lb;
    unsigned short* Wmc  = (unsigned short*)(Lb + 8192);

    // ---- phase A: write prefetched chunk c into buf[c&1] ----
    {
      int base = 256 * pp + 4 * kp;
      unsigned w0 = (pxa.x & 0xffffu) | (pxb.x << 16);
      unsigned w1 = (pxa.x >> 16) | (pxb.x & 0xffff0000u);
      unsigned w2 = (pxa.y & 0xffffu) | (pxb.y << 16);
      unsigned w3 = (pxa.y >> 16) | (pxb.y & 0xffff0000u);
      *(unsigned*)(Lb + ((base)       ^ skey)) = w0;
      *(unsigned*)(Lb + ((base + 64)  ^ skey)) = w1;
      *(unsigned*)(Lb + ((base + 128) ^ skey)) = w2;
      *(unsigned*)(Lb + ((base + 192) ^ skey)) = w3;

      int ew = R0 + c * 32 + kw;
      int dl = (pcv >> 27) & 15;
      bool mine = (ew < R1) && (dl == dw);
      unsigned short* wmp = Wmc + dw * 32 + kw;
      wmp[0]    = mine ? (unsigned short)(pwv.x & 0xffff) : 0;
      wmp[512]  = mine ? (unsigned short)(pwv.x >> 16)    : 0;
      wmp[1024] = mine ? (unsigned short)(pwv.y & 0xffff) : 0;
      wmp[1536] = mine ? (unsigned short)(pwv.y >> 16)    : 0;
      wmp[2048] = mine ? (unsigned short)(pwv.z & 0xffff) : 0;
      wmp[2560] = mine ? (unsigned short)(pwv.z >> 16)    : 0;
      wmp[3072] = mine ? (unsigned short)(pwv.w & 0xffff) : 0;
      wmp[3584] = mine ? (unsigned short)(pwv.w >> 16)    : 0;
    }
    // ---- phase B: issue chunk c+1 loads (latency hides under MFMA) ----
    if (c + 1 < nch) {
      int ebase = R0 + (c + 1) * 32;
      int e0 = ebase + 2 * kp;
      int ec0 = min(e0, R1 - 1), ec1 = min(e0 + 1, R1 - 1);
      int s0 = col[ec0] & SMASK;
      int s1 = col[ec1] & SMASK;
      pxa = *(const uint2*)(xbf + (size_t)s0 * 128 + pp * 4);
      pxb = *(const uint2*)(xbf + (size_t)s1 * 128 + pp * 4);
      int ew = min(ebase + kw, R1 - 1);
      pcv = col[ew];
      pwv = *(const uint4*)(wedge + (size_t)ew * 8);
    }
    __syncthreads();

    // ---- phase C: MFMA from buf[c&1]; wave w = head w ----
    short8 af = *(const short8*)(Wmc + w * 512 + n * 32 + 8 * q);
    accdn = __builtin_amdgcn_mfma_f32_16x16x32_bf16(af, onesf, accdn, 0, 0, 0);
#pragma unroll
    for (int ft = 0; ft < 8; ++ft) {
      int f = ft * 16 + n;
      int bb = f * 64 + 16 * q;
      bb ^= ((f >> 2) & 7) << 4;
      short8 bfr = *(const short8*)((const char*)XgTc + bb);
      accw[ft] = __builtin_amdgcn_mfma_f32_16x16x32_bf16(af, bfr, accw[ft], 0, 0, 0);
    }
  }

  __syncthreads();                         // last MFMA reads done before AggP

  // ---- epilogue 1: normalize (denominator = accdn col 0), write AggP ----
  unsigned short* AggP = (unsigned short*)LB;           // [8h][16d][136]
  {
    float dnv[4];
#pragma unroll
    for (int r = 0; r < 4; ++r) {
      float dr = __shfl(accdn[r], lane & 48);      // broadcast col-0 lane of quad
      dnv[r] = rcp_nr(dr + 1e-16f);
    }
#pragma unroll
    for (int ft = 0; ft < 8; ++ft)
#pragma unroll
      for (int r = 0; r < 4; ++r)
        AggP[w * 2176 + (4 * q + r) * 136 + ft * 16 + n] =
            f2bbits(accw[ft][r] * dnv[r]);
  }
  __syncthreads();

  // ---- phase 3a: per-head W1 GEMM -> acc2 (out1 values, registers only) ----
  int hp = w >> 1, qq = w & 1;
  floatx4 acc2[4] = {};
  {
    const unsigned short* Bp = W1frag + (size_t)hp * 16384;
#pragma unroll
    for (int ks = 0; ks < 4; ++ks) {
      short8 a2 = *(const short8*)&AggP[w * 2176 + n * 136 + ks * 32 + q * 8];
#pragma unroll
      for (int j = 0; j < 4; ++j) {
        int nt = qq * 4 + j;
        short8 b2 = *(const short8*)&Bp[((nt * 4 + ks) * 64 + lane) * 8];
        acc2[j] = __builtin_amdgcn_mfma_f32_16x16x32_bf16(a2, b2, acc2[j], 0, 0, 0);
      }
    }
  }
  float4 bq = *(const float4*)&bias_perm[hp * 128 + n * 8 + qq * 4];
  __syncthreads();       // ALL AggP reads done -> LB reusable for O1/RED/PS/PD

  // LDS overlays (all within 34816B):
  unsigned short* O1 = (unsigned short*)LB;        // [16][520] bf16 = 16640 B
  float* RED = (float*)(LB + 16640);               // [4 nt][64 lane][4] = 4096 B
  float* PSb = (float*)(LB + 20736);               // [16]
  float* PDb = (float*)(LB + 20800);               // [16]

  // ---- write O1 (bias + ELU), zero PS/PD ----
  {
#pragma unroll
    for (int r = 0; r < 4; ++r) {
      int dl = 4 * q + r;
      unsigned short* op = O1 + dl * 520 + hp * 128 + n * 8 + qq * 4;
      op[0] = f2bbits(elu1(acc2[0][r] + bq.x));
      op[1] = f2bbits(elu1(acc2[1][r] + bq.y));
      op[2] = f2bbits(elu1(acc2[2][r] + bq.z));
      op[3] = f2bbits(elu1(acc2[3][r] + bq.w));
    }
    if (t < 32) ((float*)(LB + 20736))[t] = 0.f;
  }
  __syncthreads();

  // ---- phase 3b: layer-2 GEMM [16x512]@[512x64]; wave = (nt, K-half) ----
  int nt2 = w & 3, kh = w >> 2;
  floatx4 acc3 = {};
#pragma unroll
  for (int ks8 = 0; ks8 < 8; ++ks8) {
    int ks = kh * 8 + ks8;
    short8 a3 = *(const short8*)&O1[n * 520 + ks * 32 + q * 8];
    short8 b3 = *(const short8*)&W2frag[((ks * 4 + nt2) * 64 + lane) * 8];
    acc3 = __builtin_amdgcn_mfma_f32_16x16x32_bf16(a3, b3, acc3, 0, 0, 0);
  }
  if (kh == 1) *(floatx4*)&RED[(nt2 * 64 + lane) * 4] = acc3;
  __syncthreads();

  if (kh == 0) {
    floatx4 other = *(const floatx4*)&RED[(nt2 * 64 + lane) * 4];
    float asw = att_src2[nt2 * 16 + n];
    float adw = att_dst2[nt2 * 16 + n];
    float ps[4], pd[4];
#pragma unroll
    for (int r = 0; r < 4; ++r) {
      float v = acc3[r] + other[r];
      int row = dbase + 4 * q + r;
      if (row < N) h2[(size_t)row * 64 + nt2 * 16 + n] = f2bbits(v);
      ps[r] = v * asw;
      pd[r] = v * adw;
    }
#pragma unroll
    for (int r = 0; r < 4; ++r) {
      float p = ps[r], qd = pd[r];
#pragma unroll
      for (int off2 = 1; off2 < 16; off2 <<= 1) {
        p += __shfl_xor(p, off2);
        qd += __shfl_xor(qd, off2);
      }
      if (n == 0) {
        int dl = 4 * q + r;
        atomicAdd(&PSb[dl], p);
        atomicAdd(&PDb[dl], qd);
      }
    }
  }
  __syncthreads();
  if (t < 16) {
    int row = dbase + t;
    if (row < N) {
      a_s2[row] = PSb[t];
      a_d2[row] = PDb[t];
    }
  }
}

// H=1, quarter-wave edge grouping (h2 natural layout).
__global__ void gat_agg1_kernel(const int* __restrict__ rowptr,
                                const int* __restrict__ col,
                                const float* __restrict__ a_s,
                                const float* __restrict__ a_d,
                                const unsigned short* __restrict__ hfeat,
                                const float* __restrict__ bias,
                                unsigned short* __restrict__ out, int N) {
  int wave = threadIdx.x >> 6, lane = threadIdx.x & 63;
  int d = blockIdx.x * 4 + wave;
  if (d >= N) return;
  int beg = rowptr[d], end = rowptr[d + 1];
  int qg = lane >> 4, l16 = lane & 15;
  float adv = a_d[d];
  const uint2* hfu = (const uint2*)hfeat;
  float acc[4] = {};
  float wsum = 0.f;
#pragma unroll 2
  for (int i = beg + qg; i < end; i += 4) {
    int s = col[i] & SMASK;
    float v = a_s[s] + adv;
    v = v > 0.f ? v : NEG * v;
    float wv = __expf(v);
    wsum += wv;
    uint2 u = hfu[(size_t)s * 16 + l16];
    acc[0] += wv * blo(u.x); acc[1] += wv * bhi(u.x);
    acc[2] += wv * blo(u.y); acc[3] += wv * bhi(u.y);
  }
#pragma unroll
  for (int off = 16; off <= 32; off <<= 1) {
#pragma unroll
    for (int j = 0; j < 4; ++j) acc[j] += __shfl_xor(acc[j], off);
    wsum += __shfl_xor(wsum, off);
  }
  float winv = 1.f / (wsum + 1e-16f);
  float4 bb = ((const float4*)bias)[l16];
  float r0 = elu1(acc[0] * winv + bb.x), r1 = elu1(acc[1] * winv + bb.y);
  float r2 = elu1(acc[2] * winv + bb.z), r3 = elu1(acc[3] * winv + bb.w);
  if (qg == 0) {
    uint2 o; o.x = pack2(r0, r1); o.y = pack2(r2, r3);
    ((uint2*)out)[(size_t)d * 16 + l16] = o;
  }
}

// ---------- pooling: 16 nodes per wave ----------
__global__ void pool_kernel(const unsigned short* __restrict__ out2,
                            const int* __restrict__ batch,
                            float* __restrict__ pooled, int N) {
  int wave = threadIdx.x >> 6, lane = threadIdx.x & 63;
  int seg = blockIdx.x * 4 + wave;
  int start = seg * 16;
  if (start >= N) return;
  int end = min(start + 16, N);
  int cur = batch[start];
  float acc = 0.f;
  for (int n = start; n < end; ++n) {
    int bn = batch[n];
    if (bn != cur) {
      unsafeAtomicAdd(&pooled[cur * 64 + lane], acc);
      acc = 0.f; cur = bn;
    }
    acc += bu(out2[(size_t)n * 64 + lane]);
  }
  unsafeAtomicAdd(&pooled[cur * 64 + lane], acc);
}

// ---------- MLP head + log_softmax: one block (one wave) per graph ----------
__global__ void head_kernel(const float* __restrict__ pooled,
                            const float* __restrict__ lin1_w,
                            const float* __restrict__ lin1_b,
                            const float* __restrict__ lin2_w,
                            const float* __restrict__ lin2_b,
                            const void* __restrict__ x_raw,
                            void* __restrict__ outv) {
  __shared__ float P[C];
  __shared__ float Zs[C];
  __shared__ float Ls[K];
  __shared__ float lse_s;
  __shared__ int fl;
  int isbf = detect_dev(x_raw, &fl);
  int g = blockIdx.x, t = threadIdx.x;   // 64 threads
  P[t] = pooled[g * C + t];
  __syncthreads();
  float acc = lin1_b[t];
  for (int k = 0; k < C; ++k) acc += P[k] * lin1_w[k * C + t];
  Zs[t] = elu1(acc);
  __syncthreads();
  if (t < K) {
    float a = lin2_b[t];
    for (int k = 0; k < C; ++k) a += Zs[k] * lin2_w[k * K + t];
    Ls[t] = a;
  }
  __syncthreads();
  if (t == 0) {
    float mx = -1e30f;
    for (int c = 0; c < K; ++c) mx = fmaxf(mx, Ls[c]);
    float s = 0.f;
    for (int c = 0; c < K; ++c) s += __expf(Ls[c] - mx);
    lse_s = mx + __logf(s);
  }
  __syncthreads();
  if (t < K) {
    float val = Ls[t] - lse_s;
    if (isbf) ((__hip_bfloat16*)outv)[g * K + t] = __float2bfloat16(val);
    else      ((float*)outv)[g * K + t] = val;
  }
}

extern "C" void kernel_launch(void* const* d_in, const int* in_sizes, int n_in,
                              void* d_out, int out_size, void* d_ws, size_t ws_size,
                              hipStream_t stream) {
  const void* x_raw = d_in[0];
  const int*  ei    = (const int*)d_in[1];
  const int*  batch = (const int*)d_in[2];

  const int N    = in_sizes[2];
  const int E    = in_sizes[1] / 2;
  const int Etot = E + N;
  const int nb   = (N + 255) / 256;

  float* ws   = (float*)d_ws;
  size_t off  = 0;

  float* wts = ws + off; off += 6544;
  float* b1w  = wts + 1024;
  float* as2w = wts + 1536;
  float* ad2w = wts + 1600;
  float* b2w  = wts + 1664;
  float* l1w  = wts + 1728;
  float* l1b  = wts + 5824;
  float* l2w  = wts + 5888;
  float* l2b  = wts + 6528;

  unsigned short* xbf    = (unsigned short*)(ws + off); off += (size_t)N * 64;
  unsigned short* w1frag = (unsigned short*)(ws + off); off += 32768;
  unsigned short* w2frag = (unsigned short*)(ws + off); off += 16384;
  unsigned short* vfrag  = (unsigned short*)(ws + off); off += 1024;
  unsigned short* wedge  = (unsigned short*)(ws + off); off += (size_t)Etot * 4;
  unsigned short* h2bf   = (unsigned short*)(ws + off); off += (size_t)N * 32;
  unsigned short* out2bf = (unsigned short*)(ws + off); off += (size_t)N * 32;
  float* as1  = ws + off; off += (size_t)N * H1;
  float* ad1  = ws + off; off += (size_t)N * H1;
  float* as2  = ws + off; off += (size_t)N;
  float* ad2  = ws + off; off += (size_t)N;
  float* pooled = ws + off; off += (size_t)B * C;

  int* ibase  = (int*)(ws + off);
  int* deg    = ibase;                 ibase += N;
  int* cursor = ibase;                 ibase += N;
  int* rowptr = ibase;                 ibase += N + 1;
  int* locals = ibase;                 ibase += N;
  int* bsum   = ibase;                 ibase += 256;
  int* col    = ibase;                 ibase += Etot;

  // ---- prep ----
  fused_prep_kernel<<<1024, 256, 0, stream>>>(
      x_raw, d_in[3], d_in[4], d_in[5], d_in[6], d_in[7], d_in[8], d_in[9],
      d_in[10], d_in[11], d_in[12], d_in[13], d_in[14],
      xbf, w1frag, w2frag, vfrag, wts, deg, pooled, in_sizes[0], N);

  // ---- fused: layer-1 attention scalars + degree count ----
  {
    int attBlocks = (N + 63) / 64;
    int degBlocks = (Etot + 255) / 256;
    deg_att_kernel<<<attBlocks + degBlocks, 256, 0, stream>>>(
        ei, E, Etot, deg, xbf, vfrag, as1, ad1, N, attBlocks);
  }

  // ---- CSR scans ----
  scan_block_kernel<<<nb, 256, 0, stream>>>(deg, locals, bsum, N);
  scan_finish_kernel<<<nb, 256, 0, stream>>>(locals, bsum, nb, rowptr, cursor, N, Etot);

  // ---- CSR fill + per-edge softmax weights (bf16) ----
  fill_weight_kernel<<<(Etot + 255) / 256, 256, 0, stream>>>(
      ei, E, Etot, as1, ad1, cursor, col, wedge);

  // ---- MFMA x-space aggregation + W1 GEMM + fused layer-2 GEMM ----
  aggx_gemm12_kernel<<<(N + 15) / 16, 512, 0, stream>>>(
      xbf, w1frag, rowptr, col, wedge, b1w,
      w2frag, as2w, ad2w, h2bf, as2, ad2, N);

  // ---- layer-2 aggregation ----
  gat_agg1_kernel<<<(N + 3) / 4, 256, 0, stream>>>(rowptr, col, as2, ad2, h2bf, b2w, out2bf, N);

  // ---- pool + head ----
  pool_kernel<<<(N + 63) / 64, 256, 0, stream>>>(out2bf, batch, pooled, N);
  head_kernel<<<B, 64, 0, stream>>>(pooled, l1w, l1b, l2w, l2b, x_raw, (void*)d_out);
}

// Round 14
// 267.503 us; speedup vs baseline: 1.0936x; 1.0267x over previous
//
#include <hip/hip_runtime.h>
#include <hip/hip_bf16.h>

#define DEV static __device__ __forceinline__

constexpr int F1 = 128;   // input features
constexpr int H1 = 8;     // heads layer1
constexpr int C  = 64;    // channels per head
constexpr int B  = 64;    // graphs
constexpr int K  = 10;    // classes
constexpr float NEG = 0.2f;
constexpr unsigned SMASK = 0x07FFFFFFu;   // col[] low bits = src id; bits 27-30 = dest&15

typedef __attribute__((ext_vector_type(8))) short short8;
typedef __attribute__((ext_vector_type(4))) float floatx4;

DEV float b2f(__hip_bfloat16 x) { return __bfloat162float(x); }
DEV float elu1(float v) { return v > 0.f ? v : (__expf(v) - 1.f); }
DEV unsigned short f2bbits(float f) {
  __hip_bfloat16 b = __float2bfloat16(f);
  return *(unsigned short*)&b;
}
DEV float blo(unsigned u) { return __uint_as_float(u << 16); }
DEV float bhi(unsigned u) { return __uint_as_float(u & 0xffff0000u); }
DEV float bu(unsigned short u) { return __uint_as_float(((unsigned)u) << 16); }
DEV unsigned pack2(float lo, float hi) {
  return (unsigned)f2bbits(lo) | ((unsigned)f2bbits(hi) << 16);
}
// 1/x via v_rcp_f32 + one Newton step
DEV float rcp_nr(float x) {
  float r = __builtin_amdgcn_rcpf(x);
  return r * (2.f - x * r);
}

// out1 PERMUTED layout: position p = hp*128 + l16*8 + nt  <->  natural channel
// c = hp*128 + nt*16 + l16. W2frag k-rows and b1 permuted to match.
// W1frag k is NATURAL.

// Self-detection: thread 0 samples 128 even-index bf16 reinterps of x.
DEV int detect_dev(const void* xraw, int* lds) {
  if (threadIdx.x == 0) {
    const __hip_bfloat16* xb = (const __hip_bfloat16*)xraw;
    int bad = 0;
    for (int i = 0; i < 128; ++i) {
      float v = b2f(xb[2 * i]);
      if (!(fabsf(v) < 1e4f)) bad++;
    }
    *lds = (bad < 13) ? 1 : 0;     // 1 = bf16, 0 = f32
  }
  __syncthreads();
  return *lds;
}

#define CVT(p, i) (isbf ? b2f(((const __hip_bfloat16*)(p))[i]) : ((const float*)(p))[i])

// ---------- fused prep ----------
__global__ void fused_prep_kernel(const void* x_raw, const void* w1raw,
                                  const void* as1r, const void* ad1r, const void* b1r,
                                  const void* w2raw,
                                  const void* as2r, const void* ad2r, const void* b2r,
                                  const void* l1wr, const void* l1br,
                                  const void* l2wr, const void* l2br,
                                  unsigned short* __restrict__ xbf,
                                  unsigned short* __restrict__ w1frag,
                                  unsigned short* __restrict__ w2frag,
                                  unsigned short* __restrict__ vfrag,
                                  float* __restrict__ wts,
                                  int* __restrict__ deg,
                                  float* __restrict__ pooled,
                                  int nX, int N) {
  __shared__ int fl;
  int isbf = detect_dev(x_raw, &fl);
  int gid = blockIdx.x * 256 + threadIdx.x;
  int stride = gridDim.x * 256;

  // VECTORIZED xbf copy: 16B per thread-iteration (G13)
  int ng = nX >> 3;
  if (isbf) {
    const uint4* src = (const uint4*)x_raw;
    uint4* dst = (uint4*)xbf;
    for (int i = gid; i < ng; i += stride) dst[i] = src[i];
  } else {
    const float4* src = (const float4*)x_raw;
    uint4* dst = (uint4*)xbf;
    for (int i = gid; i < ng; i += stride) {
      float4 a = src[2 * i], b = src[2 * i + 1];
      uint4 o;
      o.x = pack2(a.x, a.y); o.y = pack2(a.z, a.w);
      o.z = pack2(b.x, b.y); o.w = pack2(b.z, b.w);
      dst[i] = o;
    }
  }
  for (int i = ng * 8 + gid; i < nX; i += stride)   // tail (nX%8, normally 0)
    xbf[i] = isbf ? ((const unsigned short*)x_raw)[i]
                  : f2bbits(((const float*)x_raw)[i]);

  // b1 stored PERMUTED: wts[1024 + p] = b1[c_nat(p)]
  for (int i = gid; i < 512;  i += stride) {
    int hp = i >> 7, l16 = (i >> 3) & 15, nt = i & 7;
    int c = hp * 128 + nt * 16 + l16;
    wts[1024 + i] = CVT(b1r, c);
  }
  for (int i = gid; i < 64;   i += stride) wts[1536 + i] = CVT(as2r, i);
  for (int i = gid; i < 64;   i += stride) wts[1600 + i] = CVT(ad2r, i);
  for (int i = gid; i < 64;   i += stride) wts[1664 + i] = CVT(b2r, i);
  for (int i = gid; i < 4096; i += stride) wts[1728 + i] = CVT(l1wr, i);
  for (int i = gid; i < 64;   i += stride) wts[5824 + i] = CVT(l1br, i);
  for (int i = gid; i < 640;  i += stride) wts[5888 + i] = CVT(l2wr, i);
  for (int i = gid; i < 10;   i += stride) wts[6528 + i] = CVT(l2br, i);
  // W1frag NATURAL k
  for (int t = gid; t < 8192; t += stride) {
    int lane = t & 63, ks = (t >> 6) & 3, nt = t >> 8;
    for (int j = 0; j < 8; ++j) {
      int k = ks * 32 + (lane >> 4) * 8 + j;
      int n = nt * 16 + (lane & 15);
      w1frag[t * 8 + j] = f2bbits(CVT(w1raw, k * 512 + n));
    }
  }
  // W2frag with PERMUTED k: k index in fragment = position p; fetch W2[c_nat(p)]
  for (int t = gid; t < 4096; t += stride) {
    int lane = t & 63, nt = (t >> 6) & 3, ks = t >> 8;
    for (int j = 0; j < 8; ++j) {
      int p = ks * 32 + (lane >> 4) * 8 + j;          // permuted position
      int hp = p >> 7, pl16 = (p >> 3) & 15, pnt = p & 7;
      int k = hp * 128 + pnt * 16 + pl16;             // natural channel
      int n = nt * 16 + (lane & 15);
      w2frag[t * 8 + j] = f2bbits(CVT(w2raw, k * 64 + n));
    }
  }
  // Vfrag: B-fragment of V[128 x 16], V[:,n<8] = W1 head-n col @ att_src[n],
  // V[:,n>=8] = same with att_dst. a_s/a_d = x @ V.
  for (int t = gid; t < 2048; t += stride) {
    int j = t & 7, lane = (t >> 3) & 63, ks = t >> 9;
    int k = ks * 32 + (lane >> 4) * 8 + j;
    int n = lane & 15;
    int hh = (n < 8) ? n : (n - 8);
    float s = 0.f;
    if (n < 8) {
      for (int c = 0; c < 64; ++c)
        s += CVT(w1raw, k * 512 + hh * 64 + c) * CVT(as1r, hh * 64 + c);
    } else {
      for (int c = 0; c < 64; ++c)
        s += CVT(w1raw, k * 512 + hh * 64 + c) * CVT(ad1r, hh * 64 + c);
    }
    vfrag[(ks * 64 + lane) * 8 + j] = f2bbits(s);
  }
  for (int i = gid; i < N; i += stride) deg[i] = 0;
  for (int i = gid; i < B * C; i += stride) pooled[i] = 0.f;
}

// ---------- FUSED: att_scalars (blocks < attBlocks) + degree count ----------
__global__ __launch_bounds__(256) void deg_att_kernel(
    const int* __restrict__ ei, int E, int Etot, int* __restrict__ deg,
    const unsigned short* __restrict__ xbf,     // N x 128 bf16
    const unsigned short* __restrict__ vfrag,   // [4ks][64][8] bf16
    float* __restrict__ a_s, float* __restrict__ a_d,   // N x 8
    int N, int attBlocks) {
  if ((int)blockIdx.x >= attBlocks) {
    int e = ((int)blockIdx.x - attBlocks) * 256 + threadIdx.x;
    if (e < Etot) {
      int d = (e < E) ? ei[E + e] : e - E;
      atomicAdd(&deg[d], 1);
    }
    return;
  }
  int t = threadIdx.x, w = t >> 6, lane = t & 63;
  int quad = lane >> 4, l16 = lane & 15;
  int row0 = blockIdx.x * 64 + w * 16;

  floatx4 acc = {};
  int rl = row0 + l16; if (rl >= N) rl = N - 1;
  const unsigned short* xp = xbf + (size_t)rl * 128 + quad * 8;
#pragma unroll
  for (int ks = 0; ks < 4; ++ks) {
    short8 a = *(const short8*)(xp + ks * 32);
    short8 b = *(const short8*)&vfrag[(ks * 64 + lane) * 8];
    acc = __builtin_amdgcn_mfma_f32_16x16x32_bf16(a, b, acc, 0, 0, 0);
  }
#pragma unroll
  for (int r = 0; r < 4; ++r) {
    int row = row0 + quad * 4 + r;
    if (row < N) {
      if (l16 < 8) a_s[(size_t)row * 8 + l16] = acc[r];
      else         a_d[(size_t)row * 8 + (l16 - 8)] = acc[r];
    }
  }
}

// ---------- CSR scans ----------
__global__ void scan_block_kernel(const int* __restrict__ deg,
                                  int* __restrict__ local,
                                  int* __restrict__ bsum, int N) {
  __shared__ int tmp[256];
  int t = threadIdx.x;
  int i = blockIdx.x * 256 + t;
  int v = (i < N) ? deg[i] : 0;
  tmp[t] = v;
  __syncthreads();
  for (int off = 1; off < 256; off <<= 1) {
    int u = (t >= off) ? tmp[t - off] : 0;
    __syncthreads();
    tmp[t] += u;
    __syncthreads();
  }
  if (i < N) local[i] = tmp[t] - v;
  if (t == 255) bsum[blockIdx.x] = tmp[255];
}

__global__ void scan_finish_kernel(const int* __restrict__ local,
                                   const int* __restrict__ bsum, int nb,
                                   int* __restrict__ rowptr,
                                   int* __restrict__ cursor, int N, int Etot) {
  __shared__ int tmp[256];
  __shared__ int offs;
  int t = threadIdx.x;
  int v0 = (t < nb) ? bsum[t] : 0;
  tmp[t] = v0;
  __syncthreads();
  for (int off = 1; off < 256; off <<= 1) {
    int u = (t >= off) ? tmp[t - off] : 0;
    __syncthreads();
    tmp[t] += u;
    __syncthreads();
  }
  if (t == (int)blockIdx.x) offs = tmp[t] - v0;
  __syncthreads();
  int i = blockIdx.x * 256 + t;
  if (i < N) {
    int r = local[i] + offs;
    rowptr[i] = r;
    cursor[i] = r;
  }
  if (i == 0) rowptr[N] = Etot;
}

// ---------- CSR fill + per-edge softmax weights (bf16 x8, CSR slot order) ----
// col[pos] = src | (dest&15)<<27. No hot-address atomics (round-7 lesson).
__global__ void fill_weight_kernel(const int* __restrict__ ei, int E, int Etot,
                                   const float* __restrict__ a_s,
                                   const float* __restrict__ a_d,
                                   int* __restrict__ cursor,
                                   int* __restrict__ col,
                                   unsigned short* __restrict__ wedge) {
  int e = blockIdx.x * 256 + threadIdx.x;
  if (e >= Etot) return;
  int s, d;
  if (e < E) { s = ei[e]; d = ei[E + e]; } else { s = d = e - E; }
  int pos = atomicAdd(&cursor[d], 1);
  col[pos] = s | ((d & 15) << 27);
  float4 s0 = *(const float4*)(a_s + (size_t)s * 8);
  float4 s1 = *(const float4*)(a_s + (size_t)s * 8 + 4);
  float4 d0 = *(const float4*)(a_d + (size_t)d * 8);
  float4 d1 = *(const float4*)(a_d + (size_t)d * 8 + 4);
  float v, w0, w1, w2, w3, w4, w5, w6, w7;
  v = s0.x + d0.x; v = v > 0.f ? v : NEG * v; w0 = __expf(v);
  v = s0.y + d0.y; v = v > 0.f ? v : NEG * v; w1 = __expf(v);
  v = s0.z + d0.z; v = v > 0.f ? v : NEG * v; w2 = __expf(v);
  v = s0.w + d0.w; v = v > 0.f ? v : NEG * v; w3 = __expf(v);
  v = s1.x + d1.x; v = v > 0.f ? v : NEG * v; w4 = __expf(v);
  v = s1.y + d1.y; v = v > 0.f ? v : NEG * v; w5 = __expf(v);
  v = s1.z + d1.z; v = v > 0.f ? v : NEG * v; w6 = __expf(v);
  v = s1.w + d1.w; v = v > 0.f ? v : NEG * v; w7 = __expf(v);
  uint4 o;
  o.x = pack2(w0, w1); o.y = pack2(w2, w3);
  o.z = pack2(w4, w5); o.w = pack2(w6, w7);
  *(uint4*)(wedge + (size_t)pos * 8) = o;
}

// ---------- MFMA x-space aggregation + W1 GEMM + FUSED layer-2 GEMM ----------
// Chunk loop = round-12 optimum (chunk=32, T14 pipeline, (512,6)). Epilogue:
// out1 stays on-chip (O1 LDS tile), phase 3b runs the [16x512]@[512x64] W2
// GEMM in-block, h2 + attention scalars stored. (round-13 proven)
__global__ __launch_bounds__(512, 6) void aggx_gemm12_kernel(
    const unsigned short* __restrict__ xbf,     // N x 128 bf16
    const unsigned short* __restrict__ W1frag,  // [32][4][64][8] bf16 (natural k)
    const int* __restrict__ rowptr,
    const int* __restrict__ col,                // src | dl<<27
    const unsigned short* __restrict__ wedge,   // Etot x 8 bf16 (CSR order)
    const float* __restrict__ bias_perm,        // 512, PERMUTED
    const unsigned short* __restrict__ W2frag,  // [16ks][4nt][64][8] bf16 (perm k)
    const float* __restrict__ att_src2,         // 64
    const float* __restrict__ att_dst2,
    unsigned short* __restrict__ h2,            // N x 64 bf16 (natural)
    float* __restrict__ a_s2, float* __restrict__ a_d2,  // N
    int N) {
  __shared__ __align__(16) char LB[8 * 16 * 136 * 2];   // 34816 B, multi-role

  int t = threadIdx.x, w = t >> 6, lane = t & 63;
  int q = lane >> 4, n = lane & 15;
  int dbase = blockIdx.x * 16;

  int R0 = rowptr[dbase];
  int R1 = rowptr[min(dbase + 16, N)];
  int nch = (R1 - R0 + 31) >> 5;

  // staging ids: kp = edge-pair (0..15), pp = feature-quad (0..31)
  int kp = t >> 5, pp = t & 31;
  int skey = (pp & 7) << 4;              // = ((f>>2)&7)<<4 for f = 4*pp+df
  // wmat ids
  int dw = t >> 5, kw = t & 31;

  // ones B-fragment: B[k][n] = (n==0) ? 1.0bf16 : 0
  short8 onesf = {};
  if (n == 0) {
#pragma unroll
    for (int j = 0; j < 8; ++j) onesf[j] = (short)0x3F80;
  }

  floatx4 accw[8] = {};
  floatx4 accdn = {};

  // prefetched chunk data
  uint2 pxa, pxb;
  uint4 pwv;
  int pcv;
  {
    int e0 = R0 + 2 * kp;
    int ec0 = min(e0, R1 - 1), ec1 = min(e0 + 1, R1 - 1);
    int s0 = col[ec0] & SMASK;
    int s1 = col[ec1] & SMASK;
    pxa = *(const uint2*)(xbf + (size_t)s0 * 128 + pp * 4);
    pxb = *(const uint2*)(xbf + (size_t)s1 * 128 + pp * 4);
    int ew = min(R0 + kw, R1 - 1);
    pcv = col[ew];
    pwv = *(const uint4*)(wedge + (size_t)ew * 8);
  }

  for (int c = 0; c < nch; ++c) {
    char* Lb = LB + (c & 1) * 16384;
    unsigned short* XgTc = (unsigned short*)Lb;
    unsigned short* Wmc  = (unsigned short*)(Lb + 8192);

    // ---- phase A: write prefetched chunk c into buf[c&1] ----
    {
      int base = 256 * pp + 4 * kp;
      unsigned w0 = (pxa.x & 0xffffu) | (pxb.x << 16);
      unsigned w1 = (pxa.x >> 16) | (pxb.x & 0xffff0000u);
      unsigned w2 = (pxa.y & 0xffffu) | (pxb.y << 16);
      unsigned w3 = (pxa.y >> 16) | (pxb.y & 0xffff0000u);
      *(unsigned*)(Lb + ((base)       ^ skey)) = w0;
      *(unsigned*)(Lb + ((base + 64)  ^ skey)) = w1;
      *(unsigned*)(Lb + ((base + 128) ^ skey)) = w2;
      *(unsigned*)(Lb + ((base + 192) ^ skey)) = w3;

      int ew = R0 + c * 32 + kw;
      int dl = (pcv >> 27) & 15;
      bool mine = (ew < R1) && (dl == dw);
      unsigned short* wmp = Wmc + dw * 32 + kw;
      wmp[0]    = mine ? (unsigned short)(pwv.x & 0xffff) : 0;
      wmp[512]  = mine ? (unsigned short)(pwv.x >> 16)    : 0;
      wmp[1024] = mine ? (unsigned short)(pwv.y & 0xffff) : 0;
      wmp[1536] = mine ? (unsigned short)(pwv.y >> 16)    : 0;
      wmp[2048] = mine ? (unsigned short)(pwv.z & 0xffff) : 0;
      wmp[2560] = mine ? (unsigned short)(pwv.z >> 16)    : 0;
      wmp[3072] = mine ? (unsigned short)(pwv.w & 0xffff) : 0;
      wmp[3584] = mine ? (unsigned short)(pwv.w >> 16)    : 0;
    }
    // ---- phase B: issue chunk c+1 loads (latency hides under MFMA) ----
    if (c + 1 < nch) {
      int ebase = R0 + (c + 1) * 32;
      int e0 = ebase + 2 * kp;
      int ec0 = min(e0, R1 - 1), ec1 = min(e0 + 1, R1 - 1);
      int s0 = col[ec0] & SMASK;
      int s1 = col[ec1] & SMASK;
      pxa = *(const uint2*)(xbf + (size_t)s0 * 128 + pp * 4);
      pxb = *(const uint2*)(xbf + (size_t)s1 * 128 + pp * 4);
      int ew = min(ebase + kw, R1 - 1);
      pcv = col[ew];
      pwv = *(const uint4*)(wedge + (size_t)ew * 8);
    }
    __syncthreads();

    // ---- phase C: MFMA from buf[c&1]; wave w = head w ----
    short8 af = *(const short8*)(Wmc + w * 512 + n * 32 + 8 * q);
    accdn = __builtin_amdgcn_mfma_f32_16x16x32_bf16(af, onesf, accdn, 0, 0, 0);
#pragma unroll
    for (int ft = 0; ft < 8; ++ft) {
      int f = ft * 16 + n;
      int bb = f * 64 + 16 * q;
      bb ^= ((f >> 2) & 7) << 4;
      short8 bfr = *(const short8*)((const char*)XgTc + bb);
      accw[ft] = __builtin_amdgcn_mfma_f32_16x16x32_bf16(af, bfr, accw[ft], 0, 0, 0);
    }
  }

  __syncthreads();                         // last MFMA reads done before AggP

  // ---- epilogue 1: normalize (denominator = accdn col 0), write AggP ----
  unsigned short* AggP = (unsigned short*)LB;           // [8h][16d][136]
  {
    float dnv[4];
#pragma unroll
    for (int r = 0; r < 4; ++r) {
      float dr = __shfl(accdn[r], lane & 48);      // broadcast col-0 lane of quad
      dnv[r] = rcp_nr(dr + 1e-16f);
    }
#pragma unroll
    for (int ft = 0; ft < 8; ++ft)
#pragma unroll
      for (int r = 0; r < 4; ++r)
        AggP[w * 2176 + (4 * q + r) * 136 + ft * 16 + n] =
            f2bbits(accw[ft][r] * dnv[r]);
  }
  __syncthreads();

  // ---- phase 3a: per-head W1 GEMM -> acc2 (out1 values, registers only) ----
  int hp = w >> 1, qq = w & 1;
  floatx4 acc2[4] = {};
  {
    const unsigned short* Bp = W1frag + (size_t)hp * 16384;
#pragma unroll
    for (int ks = 0; ks < 4; ++ks) {
      short8 a2 = *(const short8*)&AggP[w * 2176 + n * 136 + ks * 32 + q * 8];
#pragma unroll
      for (int j = 0; j < 4; ++j) {
        int nt = qq * 4 + j;
        short8 b2 = *(const short8*)&Bp[((nt * 4 + ks) * 64 + lane) * 8];
        acc2[j] = __builtin_amdgcn_mfma_f32_16x16x32_bf16(a2, b2, acc2[j], 0, 0, 0);
      }
    }
  }
  float4 bq = *(const float4*)&bias_perm[hp * 128 + n * 8 + qq * 4];
  __syncthreads();       // ALL AggP reads done -> LB reusable for O1/RED/PS/PD

  // LDS overlays (all within 34816B):
  unsigned short* O1 = (unsigned short*)LB;        // [16][520] bf16 = 16640 B
  float* RED = (float*)(LB + 16640);               // [4 nt][64 lane][4] = 4096 B
  float* PSb = (float*)(LB + 20736);               // [16]
  float* PDb = (float*)(LB + 20800);               // [16]

  // ---- write O1 (bias + ELU), zero PS/PD ----
  {
#pragma unroll
    for (int r = 0; r < 4; ++r) {
      int dl = 4 * q + r;
      uint2 ov;
      ov.x = pack2(elu1(acc2[0][r] + bq.x), elu1(acc2[1][r] + bq.y));
      ov.y = pack2(elu1(acc2[2][r] + bq.z), elu1(acc2[3][r] + bq.w));
      *(uint2*)(O1 + dl * 520 + hp * 128 + n * 8 + qq * 4) = ov;
    }
    if (t < 32) ((float*)(LB + 20736))[t] = 0.f;
  }
  __syncthreads();

  // ---- phase 3b: layer-2 GEMM [16x512]@[512x64]; wave = (nt, K-half) ----
  int nt2 = w & 3, kh = w >> 2;
  floatx4 acc3 = {};
#pragma unroll
  for (int ks8 = 0; ks8 < 8; ++ks8) {
    int ks = kh * 8 + ks8;
    short8 a3 = *(const short8*)&O1[n * 520 + ks * 32 + q * 8];
    short8 b3 = *(const short8*)&W2frag[((ks * 4 + nt2) * 64 + lane) * 8];
    acc3 = __builtin_amdgcn_mfma_f32_16x16x32_bf16(a3, b3, acc3, 0, 0, 0);
  }
  if (kh == 1) *(floatx4*)&RED[(nt2 * 64 + lane) * 4] = acc3;
  __syncthreads();

  if (kh == 0) {
    floatx4 other = *(const floatx4*)&RED[(nt2 * 64 + lane) * 4];
    float asw = att_src2[nt2 * 16 + n];
    float adw = att_dst2[nt2 * 16 + n];
    float ps[4], pd[4];
#pragma unroll
    for (int r = 0; r < 4; ++r) {
      float v = acc3[r] + other[r];
      int row = dbase + 4 * q + r;
      if (row < N) h2[(size_t)row * 64 + nt2 * 16 + n] = f2bbits(v);
      ps[r] = v * asw;
      pd[r] = v * adw;
    }
#pragma unroll
    for (int r = 0; r < 4; ++r) {
      float p = ps[r], qd = pd[r];
#pragma unroll
      for (int off2 = 1; off2 < 16; off2 <<= 1) {
        p += __shfl_xor(p, off2);
        qd += __shfl_xor(qd, off2);
      }
      if (n == 0) {
        int dl = 4 * q + r;
        atomicAdd(&PSb[dl], p);
        atomicAdd(&PDb[dl], qd);
      }
    }
  }
  __syncthreads();
  if (t < 16) {
    int row = dbase + t;
    if (row < N) {
      a_s2[row] = PSb[t];
      a_d2[row] = PDb[t];
    }
  }
}

// ---------- FUSED layer-2 aggregation + pooling ----------
// Block = 256 threads (4 waves), 16 dests = one pool segment. Each wave
// handles 4 dests serially (quarter-wave edge split, h2 natural layout).
// out2 values (bf16-rounded, matching prior numerics) land in LDS; then 64
// lanes do the batch-segment walk with segment-batched atomics (pool logic).
// out2 never hits global: saves 6.4MB round-trip + one dispatch.
__global__ __launch_bounds__(256) void gat_agg1_pool_kernel(
    const int* __restrict__ rowptr,
    const int* __restrict__ col,
    const float* __restrict__ a_s,
    const float* __restrict__ a_d,
    const unsigned short* __restrict__ hfeat,   // h2: N x 64 bf16
    const float* __restrict__ bias,
    const int* __restrict__ batch,
    float* __restrict__ pooled, int N) {
  __shared__ float S[16][64];
  int wave = threadIdx.x >> 6, lane = threadIdx.x & 63;
  int qg = lane >> 4, l16 = lane & 15;
  int base = blockIdx.x * 16;
  const uint2* hfu = (const uint2*)hfeat;
  float4 bb = ((const float4*)bias)[l16];

  for (int j = 0; j < 4; ++j) {
    int d = base + wave * 4 + j;
    if (d < N) {
      int beg = rowptr[d], end = rowptr[d + 1];
      float adv = a_d[d];
      float acc0 = 0.f, acc1 = 0.f, acc2 = 0.f, acc3 = 0.f, wsum = 0.f;
#pragma unroll 2
      for (int i = beg + qg; i < end; i += 4) {
        int s = col[i] & SMASK;
        float v = a_s[s] + adv;
        v = v > 0.f ? v : NEG * v;
        float wv = __expf(v);
        wsum += wv;
        uint2 u = hfu[(size_t)s * 16 + l16];
        acc0 += wv * blo(u.x); acc1 += wv * bhi(u.x);
        acc2 += wv * blo(u.y); acc3 += wv * bhi(u.y);
      }
#pragma unroll
      for (int off = 16; off <= 32; off <<= 1) {
        acc0 += __shfl_xor(acc0, off); acc1 += __shfl_xor(acc1, off);
        acc2 += __shfl_xor(acc2, off); acc3 += __shfl_xor(acc3, off);
        wsum += __shfl_xor(wsum, off);
      }
      float winv = 1.f / (wsum + 1e-16f);
      if (qg == 0) {
        int dl = wave * 4 + j;
        // bf16-round to keep numerics identical to the old out2 path
        S[dl][4 * l16 + 0] = bu(f2bbits(elu1(acc0 * winv + bb.x)));
        S[dl][4 * l16 + 1] = bu(f2bbits(elu1(acc1 * winv + bb.y)));
        S[dl][4 * l16 + 2] = bu(f2bbits(elu1(acc2 * winv + bb.z)));
        S[dl][4 * l16 + 3] = bu(f2bbits(elu1(acc3 * winv + bb.w)));
      }
    }
  }
  __syncthreads();

  // ---- pooling walk: 64 lanes = channels, segment-batched atomics ----
  if (threadIdx.x < 64) {
    int ch = threadIdx.x;
    int cnt = min(16, N - base);
    if (cnt > 0) {
      int cur = batch[base];
      float acc = 0.f;
      for (int nn = 0; nn < cnt; ++nn) {
        int bn = batch[base + nn];
        if (bn != cur) {
          unsafeAtomicAdd(&pooled[cur * 64 + ch], acc);
          acc = 0.f; cur = bn;
        }
        acc += S[nn][ch];
      }
      unsafeAtomicAdd(&pooled[cur * 64 + ch], acc);
    }
  }
}

// ---------- MLP head + log_softmax: one block (one wave) per graph ----------
__global__ void head_kernel(const float* __restrict__ pooled,
                            const float* __restrict__ lin1_w,
                            const float* __restrict__ lin1_b,
                            const float* __restrict__ lin2_w,
                            const float* __restrict__ lin2_b,
                            const void* __restrict__ x_raw,
                            void* __restrict__ outv) {
  __shared__ float P[C];
  __shared__ float Zs[C];
  __shared__ float Ls[K];
  __shared__ float lse_s;
  __shared__ int fl;
  int isbf = detect_dev(x_raw, &fl);
  int g = blockIdx.x, t = threadIdx.x;   // 64 threads
  P[t] = pooled[g * C + t];
  __syncthreads();
  float acc = lin1_b[t];
  for (int k = 0; k < C; ++k) acc += P[k] * lin1_w[k * C + t];
  Zs[t] = elu1(acc);
  __syncthreads();
  if (t < K) {
    float a = lin2_b[t];
    for (int k = 0; k < C; ++k) a += Zs[k] * lin2_w[k * K + t];
    Ls[t] = a;
  }
  __syncthreads();
  if (t == 0) {
    float mx = -1e30f;
    for (int c = 0; c < K; ++c) mx = fmaxf(mx, Ls[c]);
    float s = 0.f;
    for (int c = 0; c < K; ++c) s += __expf(Ls[c] - mx);
    lse_s = mx + __logf(s);
  }
  __syncthreads();
  if (t < K) {
    float val = Ls[t] - lse_s;
    if (isbf) ((__hip_bfloat16*)outv)[g * K + t] = __float2bfloat16(val);
    else      ((float*)outv)[g * K + t] = val;
  }
}

extern "C" void kernel_launch(void* const* d_in, const int* in_sizes, int n_in,
                              void* d_out, int out_size, void* d_ws, size_t ws_size,
                              hipStream_t stream) {
  const void* x_raw = d_in[0];
  const int*  ei    = (const int*)d_in[1];
  const int*  batch = (const int*)d_in[2];

  const int N    = in_sizes[2];
  const int E    = in_sizes[1] / 2;
  const int Etot = E + N;
  const int nb   = (N + 255) / 256;

  float* ws   = (float*)d_ws;
  size_t off  = 0;

  float* wts = ws + off; off += 6544;
  float* b1w  = wts + 1024;
  float* as2w = wts + 1536;
  float* ad2w = wts + 1600;
  float* b2w  = wts + 1664;
  float* l1w  = wts + 1728;
  float* l1b  = wts + 5824;
  float* l2w  = wts + 5888;
  float* l2b  = wts + 6528;

  unsigned short* xbf    = (unsigned short*)(ws + off); off += (size_t)N * 64;
  unsigned short* w1frag = (unsigned short*)(ws + off); off += 32768;
  unsigned short* w2frag = (unsigned short*)(ws + off); off += 16384;
  unsigned short* vfrag  = (unsigned short*)(ws + off); off += 1024;
  unsigned short* wedge  = (unsigned short*)(ws + off); off += (size_t)Etot * 4;
  unsigned short* h2bf   = (unsigned short*)(ws + off); off += (size_t)N * 32;
  float* as1  = ws + off; off += (size_t)N * H1;
  float* ad1  = ws + off; off += (size_t)N * H1;
  float* as2  = ws + off; off += (size_t)N;
  float* ad2  = ws + off; off += (size_t)N;
  float* pooled = ws + off; off += (size_t)B * C;

  int* ibase  = (int*)(ws + off);
  int* deg    = ibase;                 ibase += N;
  int* cursor = ibase;                 ibase += N;
  int* rowptr = ibase;                 ibase += N + 1;
  int* locals = ibase;                 ibase += N;
  int* bsum   = ibase;                 ibase += 256;
  int* col    = ibase;                 ibase += Etot;

  // ---- prep ----
  fused_prep_kernel<<<1024, 256, 0, stream>>>(
      x_raw, d_in[3], d_in[4], d_in[5], d_in[6], d_in[7], d_in[8], d_in[9],
      d_in[10], d_in[11], d_in[12], d_in[13], d_in[14],
      xbf, w1frag, w2frag, vfrag, wts, deg, pooled, in_sizes[0], N);

  // ---- fused: layer-1 attention scalars + degree count ----
  {
    int attBlocks = (N + 63) / 64;
    int degBlocks = (Etot + 255) / 256;
    deg_att_kernel<<<attBlocks + degBlocks, 256, 0, stream>>>(
        ei, E, Etot, deg, xbf, vfrag, as1, ad1, N, attBlocks);
  }

  // ---- CSR scans ----
  scan_block_kernel<<<nb, 256, 0, stream>>>(deg, locals, bsum, N);
  scan_finish_kernel<<<nb, 256, 0, stream>>>(locals, bsum, nb, rowptr, cursor, N, Etot);

  // ---- CSR fill + per-edge softmax weights (bf16) ----
  fill_weight_kernel<<<(Etot + 255) / 256, 256, 0, stream>>>(
      ei, E, Etot, as1, ad1, cursor, col, wedge);

  // ---- MFMA x-space aggregation + W1 GEMM + fused layer-2 GEMM ----
  aggx_gemm12_kernel<<<(N + 15) / 16, 512, 0, stream>>>(
      xbf, w1frag, rowptr, col, wedge, b1w,
      w2frag, as2w, ad2w, h2bf, as2, ad2, N);

  // ---- fused layer-2 aggregation + pooling ----
  gat_agg1_pool_kernel<<<(N + 15) / 16, 256, 0, stream>>>(
      rowptr, col, as2, ad2, h2bf, b2w, batch, pooled, N);

  // ---- head ----
  head_kernel<<<B, 64, 0, stream>>>(pooled, l1w, l1b, l2w, l2b, x_raw, (void*)d_out);
}